// Round 1
// baseline (509.009 us; speedup 1.0000x reference)
//
#include <hip/hip_runtime.h>

#define DH    32          // d_head
#define NH    8
#define NPTS  4
#define CDIM  256
#define HW    16384       // H*W = 128*128
#define HDIM  128

typedef __attribute__((ext_vector_type(8))) short bf16x8;
typedef __attribute__((ext_vector_type(4))) float f32x4;
typedef __attribute__((ext_vector_type(8))) unsigned short u16x8;

__device__ __forceinline__ unsigned short f2bf(float f) {
  unsigned u = __float_as_uint(f);
  u += 0x7FFFu + ((u >> 16) & 1u);          // round-to-nearest-even
  return (unsigned short)(u >> 16);
}
__device__ __forceinline__ float bf2f(unsigned short s) {
  return __uint_as_float(((unsigned)s) << 16);
}

// ---------------------------------------------------------------------------
// GEMM: C(M x 256) = A(M x 256) * B(256 x 256) + bias
// ABF16: A is bf16 (mid) vs f32 (value). EPI 0: scatter to vmap bf16
// [b*8+h][n][c]; EPI 1: f32 row-major out.
// 64x64 tile, 4 waves (2x2), mfma_f32_16x16x32_bf16, K-steps of 32.
// ---------------------------------------------------------------------------
template<bool ABF16, int EPI>
__global__ __launch_bounds__(256) void gemm_k(
    const void* __restrict__ Ap, const float* __restrict__ Bw,
    const float* __restrict__ bias, void* __restrict__ Cp) {
  __shared__ unsigned short As[64][48];   // padded stride 96B (16B-aligned rows)
  __shared__ unsigned short Bs[64][48];   // transposed: Bs[col][k]
  const int mt = blockIdx.x, ct = blockIdx.y;
  const int t = threadIdx.x;
  const int lane = t & 63, wv = t >> 6;
  const int wr = wv >> 1, wc = wv & 1;
  const int l15 = lane & 15, l4 = lane >> 4;

  f32x4 acc[2][2] = {};

  for (int kk = 0; kk < 8; ++kk) {
    if (!ABF16) {
      const float* A = (const float*)Ap;
      #pragma unroll
      for (int i = 0; i < 2; ++i) {
        int f = t + i * 256;                  // 512 float4 total
        int row = f >> 3, c4 = (f & 7) << 2;
        float4 v = *(const float4*)(A + (size_t)(mt * 64 + row) * CDIM + kk * 32 + c4);
        ushort4 s4;
        s4.x = f2bf(v.x); s4.y = f2bf(v.y); s4.z = f2bf(v.z); s4.w = f2bf(v.w);
        *(ushort4*)&As[row][c4] = s4;
      }
    } else {
      const unsigned short* A = (const unsigned short*)Ap;
      int row = t >> 2, c8 = (t & 3) << 3;
      *(u16x8*)&As[row][c8] =
          *(const u16x8*)(A + (size_t)(mt * 64 + row) * CDIM + kk * 32 + c8);
    }
    #pragma unroll
    for (int i = 0; i < 2; ++i) {
      int f = t + i * 256;
      int kr = f >> 4, c4 = (f & 15) << 2;
      float4 v = *(const float4*)(Bw + (size_t)(kk * 32 + kr) * CDIM + ct * 64 + c4);
      Bs[c4 + 0][kr] = f2bf(v.x);
      Bs[c4 + 1][kr] = f2bf(v.y);
      Bs[c4 + 2][kr] = f2bf(v.z);
      Bs[c4 + 3][kr] = f2bf(v.w);
    }
    __syncthreads();
    bf16x8 a0 = *(const bf16x8*)&As[wr * 32 + l15][l4 * 8];
    bf16x8 a1 = *(const bf16x8*)&As[wr * 32 + 16 + l15][l4 * 8];
    bf16x8 b0 = *(const bf16x8*)&Bs[wc * 32 + l15][l4 * 8];
    bf16x8 b1 = *(const bf16x8*)&Bs[wc * 32 + 16 + l15][l4 * 8];
    acc[0][0] = __builtin_amdgcn_mfma_f32_16x16x32_bf16(a0, b0, acc[0][0], 0, 0, 0);
    acc[0][1] = __builtin_amdgcn_mfma_f32_16x16x32_bf16(a0, b1, acc[0][1], 0, 0, 0);
    acc[1][0] = __builtin_amdgcn_mfma_f32_16x16x32_bf16(a1, b0, acc[1][0], 0, 0, 0);
    acc[1][1] = __builtin_amdgcn_mfma_f32_16x16x32_bf16(a1, b1, acc[1][1], 0, 0, 0);
    __syncthreads();
  }
  #pragma unroll
  for (int m = 0; m < 2; ++m) {
    #pragma unroll
    for (int n = 0; n < 2; ++n) {
      #pragma unroll
      for (int r = 0; r < 4; ++r) {
        int R = mt * 64 + wr * 32 + m * 16 + l4 * 4 + r;
        int Cg = ct * 64 + wc * 32 + n * 16 + l15;
        float v = acc[m][n][r] + bias[Cg];
        if (EPI == 0) {
          int b = R >> 14, ntok = R & (HW - 1);
          int h = Cg >> 5, c = Cg & 31;
          ((unsigned short*)Cp)[((size_t)(b * NH + h) * HW + ntok) * DH + c] = f2bf(v);
        } else {
          ((float*)Cp)[(size_t)R * CDIM + Cg] = v;
        }
      }
    }
  }
}

// ---------------------------------------------------------------------------
// Offsets + attention: per wave, 4 query rows. lane j owns offset col j (64)
// and attn col j&31 (k-split across lane halves). f32 throughout.
// Writes loc (pixel coords ix,iy) [row][h][p][xy] and softmaxed attn [row][h][p].
// ---------------------------------------------------------------------------
__global__ __launch_bounds__(256) void offattn_k(
    const float* __restrict__ query, const float* __restrict__ refp,
    const float* __restrict__ Woff, const float* __restrict__ boff,
    const float* __restrict__ Wattn, const float* __restrict__ battn,
    float* __restrict__ loc, float* __restrict__ attnw) {
  __shared__ float q[16][CDIM];
  const int t = threadIdx.x;
  const int lane = t & 63, w = t >> 6;
  const int row0 = blockIdx.x * 16;
  #pragma unroll
  for (int i = 0; i < 4; ++i) {
    int f = t + i * 256;                     // 1024 float4
    int row = f >> 6, c4 = (f & 63) << 2;
    *(float4*)&q[row][c4] = *(const float4*)(query + (size_t)(row0 + row) * CDIM + c4);
  }
  __syncthreads();
  const int wrow = w << 2;
  float aoff[4] = {0.f, 0.f, 0.f, 0.f};
  float aatt[4] = {0.f, 0.f, 0.f, 0.f};
  const int j32 = lane & 31;
  const int kbase = (lane >> 5) << 7;        // 0 or 128

  for (int k4 = 0; k4 < 64; ++k4) {
    f32x4 qv[4];
    #pragma unroll
    for (int r = 0; r < 4; ++r) qv[r] = *(const f32x4*)&q[wrow + r][k4 * 4];
    #pragma unroll
    for (int i = 0; i < 4; ++i) {
      float wvv = Woff[(size_t)(k4 * 4 + i) * 64 + lane];
      #pragma unroll
      for (int r = 0; r < 4; ++r) aoff[r] += qv[r][i] * wvv;
    }
  }
  for (int k4 = 0; k4 < 32; ++k4) {
    f32x4 qv[4];
    #pragma unroll
    for (int r = 0; r < 4; ++r) qv[r] = *(const f32x4*)&q[wrow + r][kbase + k4 * 4];
    #pragma unroll
    for (int i = 0; i < 4; ++i) {
      float wvv = Wattn[(size_t)(kbase + k4 * 4 + i) * 32 + j32];
      #pragma unroll
      for (int r = 0; r < 4; ++r) aatt[r] += qv[r][i] * wvv;
    }
  }
  #pragma unroll
  for (int r = 0; r < 4; ++r) aatt[r] += __shfl_xor(aatt[r], 32);

  const float bo = boff[lane];
  const float ba = battn[j32];
  const int xy = lane & 1;
  #pragma unroll
  for (int r = 0; r < 4; ++r) {
    int row = row0 + wrow + r;
    float off = tanhf(aoff[r] + bo) * 0.5f;
    float rp = refp[(size_t)row * 2 + xy];
    // ix = (ref+off)*W - 0.5 (align_corners=False unnormalize of gx=loc01*2-1)
    float pix = (rp + off) * 128.0f - 0.5f;
    loc[(size_t)row * 64 + lane] = pix;
    float av = aatt[r] + ba;
    float m1 = fmaxf(av, __shfl_xor(av, 1));
    float mm = fmaxf(m1, __shfl_xor(m1, 2));
    float e = expf(av - mm);
    float s = e;
    s += __shfl_xor(s, 1);
    s += __shfl_xor(s, 2);
    if (lane < 32) attnw[(size_t)row * 32 + lane] = e / s;
  }
}

// ---------------------------------------------------------------------------
// Bilinear sampling + attn-weighted sum over points.
// RAW-RESHAPE QUIRK: output (b,n,h,p) uses loc of (n_l = h*2048 + (n>>3),
// h_l = n&7, p) on map (b,h). One thread per (row, head): 32-ch accumulator.
// ---------------------------------------------------------------------------
__global__ __launch_bounds__(256) void sample_k(
    const unsigned short* __restrict__ vmap, const float* __restrict__ loc,
    const float* __restrict__ attnw, unsigned short* __restrict__ mid) {
  const int t = threadIdx.x;
  const int rin = t >> 3, h = t & 7;
  const int row = blockIdx.x * 32 + rin;
  const int b = row >> 14, n = row & (HW - 1);
  const int n_l = h * 2048 + (n >> 3);
  const int h_l = n & 7;
  const float* lp = loc + ((size_t)(b * HW + n_l) * 8 + h_l) * 8;
  const float* ap = attnw + (size_t)row * 32 + h * 4;
  const unsigned short* map = vmap + (size_t)(b * NH + h) * HW * DH;

  float acc[DH];
  #pragma unroll
  for (int c = 0; c < DH; ++c) acc[c] = 0.f;

  #pragma unroll
  for (int p = 0; p < NPTS; ++p) {
    float ix = lp[p * 2], iy = lp[p * 2 + 1];
    float aw = ap[p];
    float xf = floorf(ix), yf = floorf(iy);
    float tx = ix - xf, ty = iy - yf;
    int x0 = (int)xf, y0 = (int)yf;
    float w00 = (1.f - tx) * (1.f - ty) * aw, w01 = tx * (1.f - ty) * aw;
    float w10 = (1.f - tx) * ty * aw,         w11 = tx * ty * aw;
    int xs[4] = {x0, x0 + 1, x0, x0 + 1};
    int ys[4] = {y0, y0, y0 + 1, y0 + 1};
    float wg[4] = {w00, w01, w10, w11};
    #pragma unroll
    for (int cn = 0; cn < 4; ++cn) {
      int xx = xs[cn], yy = ys[cn];
      if ((unsigned)xx < 128u && (unsigned)yy < 128u) {
        const unsigned short* cp = map + (((size_t)yy << 7) + xx) * DH;
        float wgt = wg[cn];
        #pragma unroll
        for (int i = 0; i < 4; ++i) {
          u16x8 v = *(const u16x8*)(cp + i * 8);
          #pragma unroll
          for (int jj = 0; jj < 8; ++jj) acc[i * 8 + jj] += wgt * bf2f(v[jj]);
        }
      }
    }
  }
  unsigned short* op = mid + (size_t)row * CDIM + h * DH;
  #pragma unroll
  for (int i = 0; i < 4; ++i) {
    u16x8 o;
    #pragma unroll
    for (int jj = 0; jj < 8; ++jj) o[jj] = f2bf(acc[i * 8 + jj]);
    *(u16x8*)(op + i * 8) = o;
  }
}

extern "C" void kernel_launch(void* const* d_in, const int* in_sizes, int n_in,
                              void* d_out, int out_size, void* d_ws, size_t ws_size,
                              hipStream_t stream) {
  const float* query = (const float*)d_in[0];
  const float* refp  = (const float*)d_in[1];
  const float* value = (const float*)d_in[2];
  const float* Wv    = (const float*)d_in[3];
  const float* bv    = (const float*)d_in[4];
  const float* Woff  = (const float*)d_in[5];
  const float* boff  = (const float*)d_in[6];
  const float* Wattn = (const float*)d_in[7];
  const float* battn = (const float*)d_in[8];
  const float* Wout  = (const float*)d_in[9];
  const float* bout  = (const float*)d_in[10];

  const int M = in_sizes[0] / CDIM;          // B*N = 65536

  char* ws = (char*)d_ws;
  unsigned short* vmap = (unsigned short*)ws;                 // M*256 bf16 = 33.5 MB
  size_t off1 = (size_t)M * CDIM * 2;
  float* loc = (float*)(ws + off1);                           // M*64 f32 = 16.8 MB
  size_t off2 = off1 + (size_t)M * 64 * 4;
  float* attnw = (float*)(ws + off2);                         // M*32 f32 = 8.4 MB
  size_t off3 = off2 + (size_t)M * 32 * 4;
  unsigned short* mid = (unsigned short*)(ws + off3);         // M*256 bf16 = 33.5 MB

  dim3 gg(M / 64, CDIM / 64);
  hipLaunchKernelGGL((gemm_k<false, 0>), gg, dim3(256), 0, stream, value, Wv, bv, vmap);
  hipLaunchKernelGGL(offattn_k, dim3(M / 16), dim3(256), 0, stream,
                     query, refp, Woff, boff, Wattn, battn, loc, attnw);
  hipLaunchKernelGGL(sample_k, dim3(M / 32), dim3(256), 0, stream, vmap, loc, attnw, mid);
  hipLaunchKernelGGL((gemm_k<true, 1>), gg, dim3(256), 0, stream, mid, Wout, bout, (float*)d_out);
}

// Round 2
// 268.822 us; speedup vs baseline: 1.8935x; 1.8935x over previous
//
#include <hip/hip_runtime.h>

#define DH    32          // d_head
#define NH    8
#define NPTS  4
#define CDIM  256
#define HW    16384       // H*W = 128*128
#define HDIM  128

typedef __attribute__((ext_vector_type(8))) short bf16x8;
typedef __attribute__((ext_vector_type(4))) float f32x4;
typedef __attribute__((ext_vector_type(8))) unsigned short u16x8;

__device__ __forceinline__ unsigned short f2bf(float f) {
  unsigned u = __float_as_uint(f);
  u += 0x7FFFu + ((u >> 16) & 1u);          // round-to-nearest-even
  return (unsigned short)(u >> 16);
}
__device__ __forceinline__ float bf2f(unsigned short s) {
  return __uint_as_float(((unsigned)s) << 16);
}

// ---------------------------------------------------------------------------
// GEMM: C(M x 256) = A(M x 256) * B(256 x 256) + bias
// ABF16=false: A f32 row-major (value). ABF16=true: A bf16 head-major
//   [h][M][32] (mid) — K-chunk kk is exactly head kk's 32-channel block.
// EPI 0: scatter to vmap bf16 [b*8+h][n][c]; EPI 1: f32 row-major out.
// 64x64 tile, 4 waves (2x2), mfma_f32_16x16x32_bf16, K-steps of 32.
// ---------------------------------------------------------------------------
template<bool ABF16, int EPI>
__global__ __launch_bounds__(256) void gemm_k(
    const void* __restrict__ Ap, const float* __restrict__ Bw,
    const float* __restrict__ bias, void* __restrict__ Cp, int Mrows) {
  __shared__ unsigned short As[64][48];   // padded stride 96B (16B-aligned rows)
  __shared__ unsigned short Bs[64][48];   // transposed: Bs[col][k]
  const int mt = blockIdx.x, ct = blockIdx.y;
  const int t = threadIdx.x;
  const int lane = t & 63, wv = t >> 6;
  const int wr = wv >> 1, wc = wv & 1;
  const int l15 = lane & 15, l4 = lane >> 4;

  f32x4 acc[2][2] = {};

  for (int kk = 0; kk < 8; ++kk) {
    if (!ABF16) {
      const float* A = (const float*)Ap;
      #pragma unroll
      for (int i = 0; i < 2; ++i) {
        int f = t + i * 256;                  // 512 float4 total
        int row = f >> 3, c4 = (f & 7) << 2;
        float4 v = *(const float4*)(A + (size_t)(mt * 64 + row) * CDIM + kk * 32 + c4);
        ushort4 s4;
        s4.x = f2bf(v.x); s4.y = f2bf(v.y); s4.z = f2bf(v.z); s4.w = f2bf(v.w);
        *(ushort4*)&As[row][c4] = s4;
      }
    } else {
      // head-major mid: A[((kk*M + row))*32 + c]
      const unsigned short* A = (const unsigned short*)Ap;
      int row = t >> 2, c8 = (t & 3) << 3;
      *(u16x8*)&As[row][c8] =
          *(const u16x8*)(A + ((size_t)kk * Mrows + mt * 64 + row) * 32 + c8);
    }
    #pragma unroll
    for (int i = 0; i < 2; ++i) {
      int f = t + i * 256;
      int kr = f >> 4, c4 = (f & 15) << 2;
      float4 v = *(const float4*)(Bw + (size_t)(kk * 32 + kr) * CDIM + ct * 64 + c4);
      Bs[c4 + 0][kr] = f2bf(v.x);
      Bs[c4 + 1][kr] = f2bf(v.y);
      Bs[c4 + 2][kr] = f2bf(v.z);
      Bs[c4 + 3][kr] = f2bf(v.w);
    }
    __syncthreads();
    bf16x8 a0 = *(const bf16x8*)&As[wr * 32 + l15][l4 * 8];
    bf16x8 a1 = *(const bf16x8*)&As[wr * 32 + 16 + l15][l4 * 8];
    bf16x8 b0 = *(const bf16x8*)&Bs[wc * 32 + l15][l4 * 8];
    bf16x8 b1 = *(const bf16x8*)&Bs[wc * 32 + 16 + l15][l4 * 8];
    acc[0][0] = __builtin_amdgcn_mfma_f32_16x16x32_bf16(a0, b0, acc[0][0], 0, 0, 0);
    acc[0][1] = __builtin_amdgcn_mfma_f32_16x16x32_bf16(a0, b1, acc[0][1], 0, 0, 0);
    acc[1][0] = __builtin_amdgcn_mfma_f32_16x16x32_bf16(a1, b0, acc[1][0], 0, 0, 0);
    acc[1][1] = __builtin_amdgcn_mfma_f32_16x16x32_bf16(a1, b1, acc[1][1], 0, 0, 0);
    __syncthreads();
  }
  #pragma unroll
  for (int m = 0; m < 2; ++m) {
    #pragma unroll
    for (int n = 0; n < 2; ++n) {
      #pragma unroll
      for (int r = 0; r < 4; ++r) {
        int R = mt * 64 + wr * 32 + m * 16 + l4 * 4 + r;
        int Cg = ct * 64 + wc * 32 + n * 16 + l15;
        float v = acc[m][n][r] + bias[Cg];
        if (EPI == 0) {
          int b = R >> 14, ntok = R & (HW - 1);
          int h = Cg >> 5, c = Cg & 31;
          ((unsigned short*)Cp)[((size_t)(b * NH + h) * HW + ntok) * DH + c] = f2bf(v);
        } else {
          ((float*)Cp)[(size_t)R * CDIM + Cg] = v;
        }
      }
    }
  }
}

// ---------------------------------------------------------------------------
// Offsets + attention: per wave, 4 query rows. lane j owns offset col j (64)
// and attn col j&31 (k-split across lane halves). f32 throughout.
// Writes loc (pixel coords) [row][h_l][p][xy] and attn head-major [h][M][4].
// ---------------------------------------------------------------------------
__global__ __launch_bounds__(256) void offattn_k(
    const float* __restrict__ query, const float* __restrict__ refp,
    const float* __restrict__ Woff, const float* __restrict__ boff,
    const float* __restrict__ Wattn, const float* __restrict__ battn,
    float* __restrict__ loc, float* __restrict__ attnw, int Mrows) {
  __shared__ float q[16][CDIM];
  const int t = threadIdx.x;
  const int lane = t & 63, w = t >> 6;
  const int row0 = blockIdx.x * 16;
  #pragma unroll
  for (int i = 0; i < 4; ++i) {
    int f = t + i * 256;                     // 1024 float4
    int row = f >> 6, c4 = (f & 63) << 2;
    *(float4*)&q[row][c4] = *(const float4*)(query + (size_t)(row0 + row) * CDIM + c4);
  }
  __syncthreads();
  const int wrow = w << 2;
  float aoff[4] = {0.f, 0.f, 0.f, 0.f};
  float aatt[4] = {0.f, 0.f, 0.f, 0.f};
  const int j32 = lane & 31;
  const int kbase = (lane >> 5) << 7;        // 0 or 128

  for (int k4 = 0; k4 < 64; ++k4) {
    f32x4 qv[4];
    #pragma unroll
    for (int r = 0; r < 4; ++r) qv[r] = *(const f32x4*)&q[wrow + r][k4 * 4];
    #pragma unroll
    for (int i = 0; i < 4; ++i) {
      float wvv = Woff[(size_t)(k4 * 4 + i) * 64 + lane];
      #pragma unroll
      for (int r = 0; r < 4; ++r) aoff[r] += qv[r][i] * wvv;
    }
  }
  for (int k4 = 0; k4 < 32; ++k4) {
    f32x4 qv[4];
    #pragma unroll
    for (int r = 0; r < 4; ++r) qv[r] = *(const f32x4*)&q[wrow + r][kbase + k4 * 4];
    #pragma unroll
    for (int i = 0; i < 4; ++i) {
      float wvv = Wattn[(size_t)(kbase + k4 * 4 + i) * 32 + j32];
      #pragma unroll
      for (int r = 0; r < 4; ++r) aatt[r] += qv[r][i] * wvv;
    }
  }
  #pragma unroll
  for (int r = 0; r < 4; ++r) aatt[r] += __shfl_xor(aatt[r], 32);

  const float bo = boff[lane];
  const float ba = battn[j32];
  const int xy = lane & 1;
  #pragma unroll
  for (int r = 0; r < 4; ++r) {
    int row = row0 + wrow + r;
    float off = tanhf(aoff[r] + bo) * 0.5f;
    float rp = refp[(size_t)row * 2 + xy];
    // ix = (ref+off)*W - 0.5 (align_corners=False unnormalize of gx=loc01*2-1)
    float pix = (rp + off) * 128.0f - 0.5f;
    loc[(size_t)row * 64 + lane] = pix;
    float av = aatt[r] + ba;
    float m1 = fmaxf(av, __shfl_xor(av, 1));
    float mm = fmaxf(m1, __shfl_xor(m1, 2));
    float e = expf(av - mm);
    float s = e;
    s += __shfl_xor(s, 1);
    s += __shfl_xor(s, 2);
    if (lane < 32)
      attnw[((size_t)(j32 >> 2) * Mrows + row) * 4 + (j32 & 3)] = e / s;
  }
}

// ---------------------------------------------------------------------------
// Bilinear sampling + attn-weighted sum over points.
// RAW-RESHAPE QUIRK: output (b,n,h,p) uses loc of (n_l = h*2048 + (n>>3),
// h_l = n&7, p) on map (b,h).
// Decomposition: grid (8, M/64); blockIdx.x = h (one map per XCD under
// round-robin dispatch -> 1MB working set per XCD L2). Thread (r, sub):
// 4 consecutive lanes cooperatively gather one 64B corner (16B each).
// Output mid head-major [h][M][32] -> fully coalesced 64B per 4 lanes.
// ---------------------------------------------------------------------------
__global__ __launch_bounds__(256) void sample_k(
    const unsigned short* __restrict__ vmap, const float* __restrict__ loc,
    const float* __restrict__ attnw, unsigned short* __restrict__ mid, int Mrows) {
  const int t = threadIdx.x;
  const int h = blockIdx.x;            // 0..7
  const int r = t >> 2;                // 0..63
  const int sub = t & 3;               // channel quad (8 channels, 16B)
  const int row = blockIdx.y * 64 + r;
  const int b = row >> 14, n = row & (HW - 1);
  const int n_l = h * 2048 + (n >> 3);
  const int h_l = n & 7;
  const float* lp = loc + (size_t)(b * HW + n_l) * 64 + h_l * 8;
  const f32x4 aq = *(const f32x4*)(attnw + ((size_t)h * Mrows + row) * 4);
  const unsigned short* map = vmap + (size_t)(b * NH + h) * HW * DH + sub * 8;

  f32x4 l01 = *(const f32x4*)(lp);      // p0.x p0.y p1.x p1.y
  f32x4 l23 = *(const f32x4*)(lp + 4);  // p2.x p2.y p3.x p3.y

  float acc[8];
  #pragma unroll
  for (int c = 0; c < 8; ++c) acc[c] = 0.f;

  #pragma unroll
  for (int p = 0; p < NPTS; ++p) {
    float ix = (p < 2) ? l01[(p & 1) * 2] : l23[(p & 1) * 2];
    float iy = (p < 2) ? l01[(p & 1) * 2 + 1] : l23[(p & 1) * 2 + 1];
    float aw = aq[p];
    float xf = floorf(ix), yf = floorf(iy);
    float tx = ix - xf, ty = iy - yf;
    int x0 = (int)xf, y0 = (int)yf;
    float w00 = (1.f - tx) * (1.f - ty) * aw, w01 = tx * (1.f - ty) * aw;
    float w10 = (1.f - tx) * ty * aw,         w11 = tx * ty * aw;
    int xs[4] = {x0, x0 + 1, x0, x0 + 1};
    int ys[4] = {y0, y0, y0 + 1, y0 + 1};
    float wg[4] = {w00, w01, w10, w11};
    #pragma unroll
    for (int cn = 0; cn < 4; ++cn) {
      int xx = xs[cn], yy = ys[cn];
      if ((unsigned)xx < 128u && (unsigned)yy < 128u) {
        // 4 lanes (sub=0..3) cover the 64B corner contiguously
        u16x8 v = *(const u16x8*)(map + (((size_t)yy << 7) + xx) * DH);
        float wgt = wg[cn];
        #pragma unroll
        for (int jj = 0; jj < 8; ++jj) acc[jj] += wgt * bf2f(v[jj]);
      }
    }
  }
  u16x8 o;
  #pragma unroll
  for (int jj = 0; jj < 8; ++jj) o[jj] = f2bf(acc[jj]);
  *(u16x8*)(mid + ((size_t)h * Mrows + row) * DH + sub * 8) = o;
}

extern "C" void kernel_launch(void* const* d_in, const int* in_sizes, int n_in,
                              void* d_out, int out_size, void* d_ws, size_t ws_size,
                              hipStream_t stream) {
  const float* query = (const float*)d_in[0];
  const float* refp  = (const float*)d_in[1];
  const float* value = (const float*)d_in[2];
  const float* Wv    = (const float*)d_in[3];
  const float* bv    = (const float*)d_in[4];
  const float* Woff  = (const float*)d_in[5];
  const float* boff  = (const float*)d_in[6];
  const float* Wattn = (const float*)d_in[7];
  const float* battn = (const float*)d_in[8];
  const float* Wout  = (const float*)d_in[9];
  const float* bout  = (const float*)d_in[10];

  const int M = in_sizes[0] / CDIM;          // B*N = 65536

  char* ws = (char*)d_ws;
  unsigned short* vmap = (unsigned short*)ws;                 // M*256 bf16 = 33.5 MB
  size_t off1 = (size_t)M * CDIM * 2;
  float* loc = (float*)(ws + off1);                           // M*64 f32 = 16.8 MB
  size_t off2 = off1 + (size_t)M * 64 * 4;
  float* attnw = (float*)(ws + off2);                         // [h][M][4] f32 = 8.4 MB
  size_t off3 = off2 + (size_t)M * 32 * 4;
  unsigned short* mid = (unsigned short*)(ws + off3);         // [h][M][32] bf16 = 33.5 MB

  dim3 gg(M / 64, CDIM / 64);
  hipLaunchKernelGGL((gemm_k<false, 0>), gg, dim3(256), 0, stream, value, Wv, bv, vmap, M);
  hipLaunchKernelGGL(offattn_k, dim3(M / 16), dim3(256), 0, stream,
                     query, refp, Woff, boff, Wattn, battn, loc, attnw, M);
  hipLaunchKernelGGL(sample_k, dim3(8, M / 64), dim3(256), 0, stream,
                     vmap, loc, attnw, mid, M);
  hipLaunchKernelGGL((gemm_k<true, 1>), gg, dim3(256), 0, stream, mid, Wout, bout,
                     (float*)d_out, M);
}

// Round 3
// 232.634 us; speedup vs baseline: 2.1880x; 1.1556x over previous
//
#include <hip/hip_runtime.h>

#define DH    32          // d_head
#define NH    8
#define NPTS  4
#define CDIM  256
#define HW    16384       // H*W = 128*128
#define HDIM  128

typedef __attribute__((ext_vector_type(8))) short bf16x8;
typedef __attribute__((ext_vector_type(4))) float f32x4;
typedef __attribute__((ext_vector_type(8))) unsigned short u16x8;

__device__ __forceinline__ unsigned short f2bf(float f) {
  unsigned u = __float_as_uint(f);
  u += 0x7FFFu + ((u >> 16) & 1u);          // round-to-nearest-even
  return (unsigned short)(u >> 16);
}
__device__ __forceinline__ float bf2f(unsigned short s) {
  return __uint_as_float(((unsigned)s) << 16);
}

// ---------------------------------------------------------------------------
// GEMM: C(M x 256) = A(M x 256) * B(256 x 256) + bias
// ABF16=false: A f32 row-major (value). ABF16=true: A bf16 head-major
//   [h][M][32] (mid) — K-chunk kk is exactly head kk's 32-channel block.
// EPI 0: scatter to vmap bf16 [b*8+h][n][c]; EPI 1: f32 row-major out.
// 64x64 tile, 4 waves (2x2), mfma_f32_16x16x32_bf16, K-steps of 32.
// ---------------------------------------------------------------------------
template<bool ABF16, int EPI>
__global__ __launch_bounds__(256) void gemm_k(
    const void* __restrict__ Ap, const float* __restrict__ Bw,
    const float* __restrict__ bias, void* __restrict__ Cp, int Mrows) {
  __shared__ unsigned short As[64][48];   // padded stride 96B (16B-aligned rows)
  __shared__ unsigned short Bs[64][48];   // transposed: Bs[col][k]
  const int mt = blockIdx.x, ct = blockIdx.y;
  const int t = threadIdx.x;
  const int lane = t & 63, wv = t >> 6;
  const int wr = wv >> 1, wc = wv & 1;
  const int l15 = lane & 15, l4 = lane >> 4;

  f32x4 acc[2][2] = {};

  for (int kk = 0; kk < 8; ++kk) {
    if (!ABF16) {
      const float* A = (const float*)Ap;
      #pragma unroll
      for (int i = 0; i < 2; ++i) {
        int f = t + i * 256;                  // 512 float4 total
        int row = f >> 3, c4 = (f & 7) << 2;
        float4 v = *(const float4*)(A + (size_t)(mt * 64 + row) * CDIM + kk * 32 + c4);
        ushort4 s4;
        s4.x = f2bf(v.x); s4.y = f2bf(v.y); s4.z = f2bf(v.z); s4.w = f2bf(v.w);
        *(ushort4*)&As[row][c4] = s4;
      }
    } else {
      // head-major mid: A[((kk*M + row))*32 + c]
      const unsigned short* A = (const unsigned short*)Ap;
      int row = t >> 2, c8 = (t & 3) << 3;
      *(u16x8*)&As[row][c8] =
          *(const u16x8*)(A + ((size_t)kk * Mrows + mt * 64 + row) * 32 + c8);
    }
    #pragma unroll
    for (int i = 0; i < 2; ++i) {
      int f = t + i * 256;
      int kr = f >> 4, c4 = (f & 15) << 2;
      float4 v = *(const float4*)(Bw + (size_t)(kk * 32 + kr) * CDIM + ct * 64 + c4);
      Bs[c4 + 0][kr] = f2bf(v.x);
      Bs[c4 + 1][kr] = f2bf(v.y);
      Bs[c4 + 2][kr] = f2bf(v.z);
      Bs[c4 + 3][kr] = f2bf(v.w);
    }
    __syncthreads();
    bf16x8 a0 = *(const bf16x8*)&As[wr * 32 + l15][l4 * 8];
    bf16x8 a1 = *(const bf16x8*)&As[wr * 32 + 16 + l15][l4 * 8];
    bf16x8 b0 = *(const bf16x8*)&Bs[wc * 32 + l15][l4 * 8];
    bf16x8 b1 = *(const bf16x8*)&Bs[wc * 32 + 16 + l15][l4 * 8];
    acc[0][0] = __builtin_amdgcn_mfma_f32_16x16x32_bf16(a0, b0, acc[0][0], 0, 0, 0);
    acc[0][1] = __builtin_amdgcn_mfma_f32_16x16x32_bf16(a0, b1, acc[0][1], 0, 0, 0);
    acc[1][0] = __builtin_amdgcn_mfma_f32_16x16x32_bf16(a1, b0, acc[1][0], 0, 0, 0);
    acc[1][1] = __builtin_amdgcn_mfma_f32_16x16x32_bf16(a1, b1, acc[1][1], 0, 0, 0);
    __syncthreads();
  }
  #pragma unroll
  for (int m = 0; m < 2; ++m) {
    #pragma unroll
    for (int n = 0; n < 2; ++n) {
      #pragma unroll
      for (int r = 0; r < 4; ++r) {
        int R = mt * 64 + wr * 32 + m * 16 + l4 * 4 + r;
        int Cg = ct * 64 + wc * 32 + n * 16 + l15;
        float v = acc[m][n][r] + bias[Cg];
        if (EPI == 0) {
          int b = R >> 14, ntok = R & (HW - 1);
          int h = Cg >> 5, c = Cg & 31;
          ((unsigned short*)Cp)[((size_t)(b * NH + h) * HW + ntok) * DH + c] = f2bf(v);
        } else {
          ((float*)Cp)[(size_t)R * CDIM + Cg] = v;
        }
      }
    }
  }
}

// ---------------------------------------------------------------------------
// Offsets + attention via split-precision bf16 MFMA.
// C(M x 96) = q(M x 256) @ [Woff | Wattn](256 x 96). q and W are split into
// hi/lo bf16 (exact residual); acc = qh*wh + ql*wh + qh*wl gives ~2^-17 rel
// error (needed: bf16-only offsets would give ~0.02px coordinate error ->
// output absmax ~0.08 > 0.037 threshold).
// Block: 64 rows, 4 waves (2x2), wave tile 32r x 48c (3 col-tiles of 16).
// Epilogue: cols<64 -> tanh offsets -> pixel coords in loc[row][64];
// cols>=64 -> 4-wide softmax via shfl_xor(1,2) -> attnw [h][M][4].
// ---------------------------------------------------------------------------
__global__ __launch_bounds__(256) void offattn_k(
    const float* __restrict__ query, const float* __restrict__ refp,
    const float* __restrict__ Woff, const float* __restrict__ boff,
    const float* __restrict__ Wattn, const float* __restrict__ battn,
    float* __restrict__ loc, float* __restrict__ attnw, int Mrows) {
  __shared__ unsigned short Ah[64][40], Al[64][40];    // [row][k], stride 80B
  __shared__ unsigned short Bh[96][40], Bl[96][40];    // [col][k]
  const int t = threadIdx.x;
  const int lane = t & 63, wv = t >> 6;
  const int wr = wv >> 1, wc = wv & 1;
  const int l15 = lane & 15, l4 = lane >> 4;
  const int row0 = blockIdx.x * 64;

  f32x4 acc[2][3] = {};

  for (int kk = 0; kk < 8; ++kk) {
    // stage A: 64 rows x 32 k of query (f32), split hi/lo
    #pragma unroll
    for (int i = 0; i < 2; ++i) {
      int ff = t + i * 256;                 // 512 float4
      int row = ff >> 3, c4 = (ff & 7) << 2;
      float4 v = *(const float4*)(query + (size_t)(row0 + row) * CDIM + kk * 32 + c4);
      ushort4 hi, lo;
      hi.x = f2bf(v.x); lo.x = f2bf(v.x - bf2f(hi.x));
      hi.y = f2bf(v.y); lo.y = f2bf(v.y - bf2f(hi.y));
      hi.z = f2bf(v.z); lo.z = f2bf(v.z - bf2f(hi.z));
      hi.w = f2bf(v.w); lo.w = f2bf(v.w - bf2f(hi.w));
      *(ushort4*)&Ah[row][c4] = hi;
      *(ushort4*)&Al[row][c4] = lo;
    }
    // stage W: 32 k x 96 cols (Woff cols 0..63, Wattn cols 64..95), transposed
    #pragma unroll
    for (int i = 0; i < 3; ++i) {
      int ff = t + i * 256;                 // 768 float4
      int kr = ff / 24, c4 = (ff % 24) << 2;
      int kg = kk * 32 + kr;
      float4 v = (c4 < 64)
          ? *(const float4*)(Woff + (size_t)kg * 64 + c4)
          : *(const float4*)(Wattn + (size_t)kg * 32 + (c4 - 64));
      #pragma unroll
      for (int u = 0; u < 4; ++u) {
        float x = (u == 0) ? v.x : (u == 1) ? v.y : (u == 2) ? v.z : v.w;
        unsigned short h = f2bf(x);
        Bh[c4 + u][kr] = h;
        Bl[c4 + u][kr] = f2bf(x - bf2f(h));
      }
    }
    __syncthreads();
    bf16x8 ah0 = *(const bf16x8*)&Ah[wr * 32 + l15][l4 * 8];
    bf16x8 ah1 = *(const bf16x8*)&Ah[wr * 32 + 16 + l15][l4 * 8];
    bf16x8 al0 = *(const bf16x8*)&Al[wr * 32 + l15][l4 * 8];
    bf16x8 al1 = *(const bf16x8*)&Al[wr * 32 + 16 + l15][l4 * 8];
    #pragma unroll
    for (int c = 0; c < 3; ++c) {
      bf16x8 bh = *(const bf16x8*)&Bh[wc * 48 + c * 16 + l15][l4 * 8];
      bf16x8 bl = *(const bf16x8*)&Bl[wc * 48 + c * 16 + l15][l4 * 8];
      acc[0][c] = __builtin_amdgcn_mfma_f32_16x16x32_bf16(ah0, bh, acc[0][c], 0, 0, 0);
      acc[0][c] = __builtin_amdgcn_mfma_f32_16x16x32_bf16(al0, bh, acc[0][c], 0, 0, 0);
      acc[0][c] = __builtin_amdgcn_mfma_f32_16x16x32_bf16(ah0, bl, acc[0][c], 0, 0, 0);
      acc[1][c] = __builtin_amdgcn_mfma_f32_16x16x32_bf16(ah1, bh, acc[1][c], 0, 0, 0);
      acc[1][c] = __builtin_amdgcn_mfma_f32_16x16x32_bf16(al1, bh, acc[1][c], 0, 0, 0);
      acc[1][c] = __builtin_amdgcn_mfma_f32_16x16x32_bf16(ah1, bl, acc[1][c], 0, 0, 0);
    }
    __syncthreads();
  }

  // epilogue
  #pragma unroll
  for (int c = 0; c < 3; ++c) {
    const int ctile = wc * 3 + c;           // 0..5
    const int col = ctile * 16 + l15;       // 0..95
    const float bias = (ctile < 4) ? boff[col] : battn[col - 64];
    #pragma unroll
    for (int m = 0; m < 2; ++m) {
      #pragma unroll
      for (int r = 0; r < 4; ++r) {
        const int row = row0 + wr * 32 + m * 16 + l4 * 4 + r;
        float v = acc[m][c][r] + bias;
        if (ctile < 4) {
          // offset col: j = h_l*8 + p*2 + xy, xy = col&1
          float off = tanhf(v) * 0.5f;
          float rp = refp[(size_t)row * 2 + (col & 1)];
          loc[(size_t)row * 64 + col] = (rp + off) * 128.0f - 0.5f;
        } else {
          // attn col j = col-64; softmax over groups of 4 (j&3 <-> lane bits 0,1)
          int j = col - 64;
          float m1 = fmaxf(v, __shfl_xor(v, 1));
          float mm = fmaxf(m1, __shfl_xor(m1, 2));
          float e = expf(v - mm);
          float s = e;
          s += __shfl_xor(s, 1);
          s += __shfl_xor(s, 2);
          attnw[((size_t)(j >> 2) * Mrows + row) * 4 + (j & 3)] = e / s;
        }
      }
    }
  }
}

// ---------------------------------------------------------------------------
// Bilinear sampling + attn-weighted sum over points.
// RAW-RESHAPE QUIRK: output (b,n,h,p) uses loc of (n_l = h*2048 + (n>>3),
// h_l = n&7, p) on map (b,h). grid (8, M/64); blockIdx.x = h (head-per-XCD
// L2 locality). 4 consecutive lanes gather one 64B corner cooperatively.
// ---------------------------------------------------------------------------
__global__ __launch_bounds__(256) void sample_k(
    const unsigned short* __restrict__ vmap, const float* __restrict__ loc,
    const float* __restrict__ attnw, unsigned short* __restrict__ mid, int Mrows) {
  const int t = threadIdx.x;
  const int h = blockIdx.x;            // 0..7
  const int r = t >> 2;                // 0..63
  const int sub = t & 3;               // channel quad (8 channels, 16B)
  const int row = blockIdx.y * 64 + r;
  const int b = row >> 14, n = row & (HW - 1);
  const int n_l = h * 2048 + (n >> 3);
  const int h_l = n & 7;
  const float* lp = loc + (size_t)(b * HW + n_l) * 64 + h_l * 8;
  const f32x4 aq = *(const f32x4*)(attnw + ((size_t)h * Mrows + row) * 4);
  const unsigned short* map = vmap + (size_t)(b * NH + h) * HW * DH + sub * 8;

  f32x4 l01 = *(const f32x4*)(lp);      // p0.x p0.y p1.x p1.y
  f32x4 l23 = *(const f32x4*)(lp + 4);  // p2.x p2.y p3.x p3.y

  float acc[8];
  #pragma unroll
  for (int c = 0; c < 8; ++c) acc[c] = 0.f;

  #pragma unroll
  for (int p = 0; p < NPTS; ++p) {
    float ix = (p < 2) ? l01[(p & 1) * 2] : l23[(p & 1) * 2];
    float iy = (p < 2) ? l01[(p & 1) * 2 + 1] : l23[(p & 1) * 2 + 1];
    float aw = aq[p];
    float xf = floorf(ix), yf = floorf(iy);
    float tx = ix - xf, ty = iy - yf;
    int x0 = (int)xf, y0 = (int)yf;
    float w00 = (1.f - tx) * (1.f - ty) * aw, w01 = tx * (1.f - ty) * aw;
    float w10 = (1.f - tx) * ty * aw,         w11 = tx * ty * aw;
    int xs[4] = {x0, x0 + 1, x0, x0 + 1};
    int ys[4] = {y0, y0, y0 + 1, y0 + 1};
    float wg[4] = {w00, w01, w10, w11};
    #pragma unroll
    for (int cn = 0; cn < 4; ++cn) {
      int xx = xs[cn], yy = ys[cn];
      if ((unsigned)xx < 128u && (unsigned)yy < 128u) {
        u16x8 v = *(const u16x8*)(map + (((size_t)yy << 7) + xx) * DH);
        float wgt = wg[cn];
        #pragma unroll
        for (int jj = 0; jj < 8; ++jj) acc[jj] += wgt * bf2f(v[jj]);
      }
    }
  }
  u16x8 o;
  #pragma unroll
  for (int jj = 0; jj < 8; ++jj) o[jj] = f2bf(acc[jj]);
  *(u16x8*)(mid + ((size_t)h * Mrows + row) * DH + sub * 8) = o;
}

extern "C" void kernel_launch(void* const* d_in, const int* in_sizes, int n_in,
                              void* d_out, int out_size, void* d_ws, size_t ws_size,
                              hipStream_t stream) {
  const float* query = (const float*)d_in[0];
  const float* refp  = (const float*)d_in[1];
  const float* value = (const float*)d_in[2];
  const float* Wv    = (const float*)d_in[3];
  const float* bv    = (const float*)d_in[4];
  const float* Woff  = (const float*)d_in[5];
  const float* boff  = (const float*)d_in[6];
  const float* Wattn = (const float*)d_in[7];
  const float* battn = (const float*)d_in[8];
  const float* Wout  = (const float*)d_in[9];
  const float* bout  = (const float*)d_in[10];

  const int M = in_sizes[0] / CDIM;          // B*N = 65536

  char* ws = (char*)d_ws;
  unsigned short* vmap = (unsigned short*)ws;                 // M*256 bf16 = 33.5 MB
  size_t off1 = (size_t)M * CDIM * 2;
  float* loc = (float*)(ws + off1);                           // M*64 f32 = 16.8 MB
  size_t off2 = off1 + (size_t)M * 64 * 4;
  float* attnw = (float*)(ws + off2);                         // [h][M][4] f32 = 8.4 MB
  size_t off3 = off2 + (size_t)M * 32 * 4;
  unsigned short* mid = (unsigned short*)(ws + off3);         // [h][M][32] bf16 = 33.5 MB

  dim3 gg(M / 64, CDIM / 64);
  hipLaunchKernelGGL((gemm_k<false, 0>), gg, dim3(256), 0, stream, value, Wv, bv, vmap, M);
  hipLaunchKernelGGL(offattn_k, dim3(M / 64), dim3(256), 0, stream,
                     query, refp, Woff, boff, Wattn, battn, loc, attnw, M);
  hipLaunchKernelGGL(sample_k, dim3(8, M / 64), dim3(256), 0, stream,
                     vmap, loc, attnw, mid, M);
  hipLaunchKernelGGL((gemm_k<true, 1>), gg, dim3(256), 0, stream, mid, Wout, bout,
                     (float*)d_out, M);
}

// Round 4
// 156.605 us; speedup vs baseline: 3.2503x; 1.4855x over previous
//
#include <hip/hip_runtime.h>

#define DH    32          // d_head
#define NH    8
#define NPTS  4
#define CDIM  256
#define HW    16384       // H*W = 128*128
#define HDIM  128

typedef __attribute__((ext_vector_type(8))) short bf16x8;
typedef __attribute__((ext_vector_type(4))) float f32x4;
typedef __attribute__((ext_vector_type(8))) unsigned short u16x8;

__device__ __forceinline__ unsigned short f2bf(float f) {
  unsigned u = __float_as_uint(f);
  u += 0x7FFFu + ((u >> 16) & 1u);          // round-to-nearest-even
  return (unsigned short)(u >> 16);
}
__device__ __forceinline__ float bf2f(unsigned short s) {
  return __uint_as_float(((unsigned)s) << 16);
}

// ---------------------------------------------------------------------------
// One-shot weight prep: f32 [k][col] (256x256) -> bf16 transposed [col][k].
// 64x64 LDS-tiled transpose; grid (4,4,2), z selects {Wv, Wout}.
// ---------------------------------------------------------------------------
__global__ __launch_bounds__(256) void prep_k(
    const float* __restrict__ W0, const float* __restrict__ W1,
    unsigned short* __restrict__ T0, unsigned short* __restrict__ T1) {
  __shared__ unsigned short tile[64][68];
  const float* W = blockIdx.z ? W1 : W0;
  unsigned short* T = blockIdx.z ? T1 : T0;
  const int r0 = blockIdx.x * 64, c0 = blockIdx.y * 64;
  const int t = threadIdx.x;
  #pragma unroll
  for (int i = 0; i < 4; ++i) {
    int f = t + i * 256;                     // 1024 float4
    int r = f >> 4, c4 = (f & 15) << 2;
    float4 v = *(const float4*)(W + (size_t)(r0 + r) * CDIM + c0 + c4);
    ushort4 s;
    s.x = f2bf(v.x); s.y = f2bf(v.y); s.z = f2bf(v.z); s.w = f2bf(v.w);
    *(ushort4*)&tile[r][c4] = s;
  }
  __syncthreads();
  #pragma unroll
  for (int i = 0; i < 4; ++i) {
    int f = t + i * 256;
    int c = f >> 4, r4 = (f & 15) << 2;
    ushort4 o;
    o.x = tile[r4 + 0][c]; o.y = tile[r4 + 1][c];
    o.z = tile[r4 + 2][c]; o.w = tile[r4 + 3][c];
    *(ushort4*)(T + (size_t)(c0 + c) * CDIM + r0 + r4) = o;
  }
}

// ---------------------------------------------------------------------------
// GEMM: C(M x 256) = A(M x 256) * B(256 x 256) + bias
// B: bf16 pre-transposed [col][k]. ABF16=false: A f32 row-major (value),
// converted during staging. ABF16=true: A bf16 head-major [h][M][32] (mid).
// EPI 0: scatter to vmap bf16 [b*8+h][n][c]; EPI 1: f32 row-major out.
// 128x128 tile, 4 waves (2x2), wave tile 64x64 (4x4 frags), BK=32.
// LDS rows padded to 36 shorts (18 words, odd stride) -> b128 reads at the
// 2-lane/bank free floor; all staging stores >= 8B vectors.
// ---------------------------------------------------------------------------
template<bool ABF16, int EPI>
__global__ __launch_bounds__(256) void gemm_k(
    const void* __restrict__ Ap, const unsigned short* __restrict__ Bt,
    const float* __restrict__ bias, void* __restrict__ Cp, int Mrows) {
  __shared__ unsigned short As[128][36];
  __shared__ unsigned short Bs[128][36];
  const int mt = blockIdx.x, ct = blockIdx.y;
  const int t = threadIdx.x;
  const int lane = t & 63, wv = t >> 6;
  const int wr = wv >> 1, wc = wv & 1;
  const int l15 = lane & 15, l4 = lane >> 4;

  f32x4 acc[4][4] = {};

  for (int kk = 0; kk < 8; ++kk) {
    if (!ABF16) {
      const float* A = (const float*)Ap;
      #pragma unroll
      for (int i = 0; i < 4; ++i) {
        int f = t + i * 256;                  // 1024 float4: 128 rows x 8
        int row = f >> 3, c4 = (f & 7) << 2;
        float4 v = *(const float4*)(A + (size_t)(mt * 128 + row) * CDIM + kk * 32 + c4);
        ushort4 s;
        s.x = f2bf(v.x); s.y = f2bf(v.y); s.z = f2bf(v.z); s.w = f2bf(v.w);
        *(ushort4*)&As[row][c4] = s;
      }
    } else {
      const unsigned short* A = (const unsigned short*)Ap;
      #pragma unroll
      for (int i = 0; i < 2; ++i) {
        int f = t + i * 256;                  // 512 u16x8: 128 rows x 4
        int row = f >> 2, c8 = (f & 3) << 3;
        *(u16x8*)&As[row][c8] =
            *(const u16x8*)(A + ((size_t)kk * Mrows + mt * 128 + row) * 32 + c8);
      }
    }
    #pragma unroll
    for (int i = 0; i < 2; ++i) {
      int f = t + i * 256;                    // 512 u16x8: 128 cols x 4
      int col = f >> 2, k8 = (f & 3) << 3;
      *(u16x8*)&Bs[col][k8] =
          *(const u16x8*)(Bt + (size_t)(ct * 128 + col) * CDIM + kk * 32 + k8);
    }
    __syncthreads();
    bf16x8 a[4], b[4];
    #pragma unroll
    for (int m = 0; m < 4; ++m) a[m] = *(const bf16x8*)&As[wr * 64 + m * 16 + l15][l4 * 8];
    #pragma unroll
    for (int n = 0; n < 4; ++n) b[n] = *(const bf16x8*)&Bs[wc * 64 + n * 16 + l15][l4 * 8];
    #pragma unroll
    for (int m = 0; m < 4; ++m)
      #pragma unroll
      for (int n = 0; n < 4; ++n)
        acc[m][n] = __builtin_amdgcn_mfma_f32_16x16x32_bf16(a[m], b[n], acc[m][n], 0, 0, 0);
    __syncthreads();
  }
  #pragma unroll
  for (int m = 0; m < 4; ++m) {
    #pragma unroll
    for (int n = 0; n < 4; ++n) {
      #pragma unroll
      for (int r = 0; r < 4; ++r) {
        int R = mt * 128 + wr * 64 + m * 16 + l4 * 4 + r;
        int Cg = ct * 128 + wc * 64 + n * 16 + l15;
        float v = acc[m][n][r] + bias[Cg];
        if (EPI == 0) {
          int b2 = R >> 14, ntok = R & (HW - 1);
          int h = Cg >> 5, c = Cg & 31;
          ((unsigned short*)Cp)[((size_t)(b2 * NH + h) * HW + ntok) * DH + c] = f2bf(v);
        } else {
          ((float*)Cp)[(size_t)R * CDIM + Cg] = v;
        }
      }
    }
  }
}

// ---------------------------------------------------------------------------
// Offsets + attention via split-precision bf16 MFMA (qh*wh + ql*wh + qh*wl).
// Block: 64 rows, 4 waves (2x2), wave tile 32r x 48c.
// Epilogue: cols<64 -> tanh offsets -> pixel coords; cols>=64 -> 4-wide
// softmax via shfl_xor(1,2) -> attnw [h][M][4].
// ---------------------------------------------------------------------------
__global__ __launch_bounds__(256) void offattn_k(
    const float* __restrict__ query, const float* __restrict__ refp,
    const float* __restrict__ Woff, const float* __restrict__ boff,
    const float* __restrict__ Wattn, const float* __restrict__ battn,
    float* __restrict__ loc, float* __restrict__ attnw, int Mrows) {
  __shared__ unsigned short Ah[64][40], Al[64][40];    // [row][k]
  __shared__ unsigned short Bh[96][40], Bl[96][40];    // [col][k]
  const int t = threadIdx.x;
  const int lane = t & 63, wv = t >> 6;
  const int wr = wv >> 1, wc = wv & 1;
  const int l15 = lane & 15, l4 = lane >> 4;
  const int row0 = blockIdx.x * 64;

  f32x4 acc[2][3] = {};

  for (int kk = 0; kk < 8; ++kk) {
    #pragma unroll
    for (int i = 0; i < 2; ++i) {
      int ff = t + i * 256;                 // 512 float4
      int row = ff >> 3, c4 = (ff & 7) << 2;
      float4 v = *(const float4*)(query + (size_t)(row0 + row) * CDIM + kk * 32 + c4);
      ushort4 hi, lo;
      hi.x = f2bf(v.x); lo.x = f2bf(v.x - bf2f(hi.x));
      hi.y = f2bf(v.y); lo.y = f2bf(v.y - bf2f(hi.y));
      hi.z = f2bf(v.z); lo.z = f2bf(v.z - bf2f(hi.z));
      hi.w = f2bf(v.w); lo.w = f2bf(v.w - bf2f(hi.w));
      *(ushort4*)&Ah[row][c4] = hi;
      *(ushort4*)&Al[row][c4] = lo;
    }
    #pragma unroll
    for (int i = 0; i < 3; ++i) {
      int ff = t + i * 256;                 // 768 float4
      int kr = ff / 24, c4 = (ff % 24) << 2;
      int kg = kk * 32 + kr;
      float4 v = (c4 < 64)
          ? *(const float4*)(Woff + (size_t)kg * 64 + c4)
          : *(const float4*)(Wattn + (size_t)kg * 32 + (c4 - 64));
      #pragma unroll
      for (int u = 0; u < 4; ++u) {
        float x = (u == 0) ? v.x : (u == 1) ? v.y : (u == 2) ? v.z : v.w;
        unsigned short h = f2bf(x);
        Bh[c4 + u][kr] = h;
        Bl[c4 + u][kr] = f2bf(x - bf2f(h));
      }
    }
    __syncthreads();
    bf16x8 ah0 = *(const bf16x8*)&Ah[wr * 32 + l15][l4 * 8];
    bf16x8 ah1 = *(const bf16x8*)&Ah[wr * 32 + 16 + l15][l4 * 8];
    bf16x8 al0 = *(const bf16x8*)&Al[wr * 32 + l15][l4 * 8];
    bf16x8 al1 = *(const bf16x8*)&Al[wr * 32 + 16 + l15][l4 * 8];
    #pragma unroll
    for (int c = 0; c < 3; ++c) {
      bf16x8 bh = *(const bf16x8*)&Bh[wc * 48 + c * 16 + l15][l4 * 8];
      bf16x8 bl = *(const bf16x8*)&Bl[wc * 48 + c * 16 + l15][l4 * 8];
      acc[0][c] = __builtin_amdgcn_mfma_f32_16x16x32_bf16(ah0, bh, acc[0][c], 0, 0, 0);
      acc[0][c] = __builtin_amdgcn_mfma_f32_16x16x32_bf16(al0, bh, acc[0][c], 0, 0, 0);
      acc[0][c] = __builtin_amdgcn_mfma_f32_16x16x32_bf16(ah0, bl, acc[0][c], 0, 0, 0);
      acc[1][c] = __builtin_amdgcn_mfma_f32_16x16x32_bf16(ah1, bh, acc[1][c], 0, 0, 0);
      acc[1][c] = __builtin_amdgcn_mfma_f32_16x16x32_bf16(al1, bh, acc[1][c], 0, 0, 0);
      acc[1][c] = __builtin_amdgcn_mfma_f32_16x16x32_bf16(ah1, bl, acc[1][c], 0, 0, 0);
    }
    __syncthreads();
  }

  #pragma unroll
  for (int c = 0; c < 3; ++c) {
    const int ctile = wc * 3 + c;           // 0..5
    const int col = ctile * 16 + l15;       // 0..95
    const float bias = (ctile < 4) ? boff[col] : battn[col - 64];
    #pragma unroll
    for (int m = 0; m < 2; ++m) {
      #pragma unroll
      for (int r = 0; r < 4; ++r) {
        const int row = row0 + wr * 32 + m * 16 + l4 * 4 + r;
        float v = acc[m][c][r] + bias;
        if (ctile < 4) {
          float off = tanhf(v) * 0.5f;
          float rp = refp[(size_t)row * 2 + (col & 1)];
          loc[(size_t)row * 64 + col] = (rp + off) * 128.0f - 0.5f;
        } else {
          int j = col - 64;
          float m1 = fmaxf(v, __shfl_xor(v, 1));
          float mm = fmaxf(m1, __shfl_xor(m1, 2));
          float e = expf(v - mm);
          float s = e;
          s += __shfl_xor(s, 1);
          s += __shfl_xor(s, 2);
          attnw[((size_t)(j >> 2) * Mrows + row) * 4 + (j & 3)] = e / s;
        }
      }
    }
  }
}

// ---------------------------------------------------------------------------
// Bilinear sampling + attn-weighted sum over points.
// RAW-RESHAPE QUIRK: output (b,n,h,p) uses loc of (n_l = h*2048 + (n>>3),
// h_l = n&7, p) on map (b,h). grid (8, M/64); blockIdx.x = h (head-per-XCD
// L2 locality). 4 consecutive lanes gather one 64B corner cooperatively.
// ---------------------------------------------------------------------------
__global__ __launch_bounds__(256) void sample_k(
    const unsigned short* __restrict__ vmap, const float* __restrict__ loc,
    const float* __restrict__ attnw, unsigned short* __restrict__ mid, int Mrows) {
  const int t = threadIdx.x;
  const int h = blockIdx.x;            // 0..7
  const int r = t >> 2;                // 0..63
  const int sub = t & 3;               // channel quad (8 channels, 16B)
  const int row = blockIdx.y * 64 + r;
  const int b = row >> 14, n = row & (HW - 1);
  const int n_l = h * 2048 + (n >> 3);
  const int h_l = n & 7;
  const float* lp = loc + (size_t)(b * HW + n_l) * 64 + h_l * 8;
  const f32x4 aq = *(const f32x4*)(attnw + ((size_t)h * Mrows + row) * 4);
  const unsigned short* map = vmap + (size_t)(b * NH + h) * HW * DH + sub * 8;

  f32x4 l01 = *(const f32x4*)(lp);      // p0.x p0.y p1.x p1.y
  f32x4 l23 = *(const f32x4*)(lp + 4);  // p2.x p2.y p3.x p3.y

  float acc[8];
  #pragma unroll
  for (int c = 0; c < 8; ++c) acc[c] = 0.f;

  #pragma unroll
  for (int p = 0; p < NPTS; ++p) {
    float ix = (p < 2) ? l01[(p & 1) * 2] : l23[(p & 1) * 2];
    float iy = (p < 2) ? l01[(p & 1) * 2 + 1] : l23[(p & 1) * 2 + 1];
    float aw = aq[p];
    float xf = floorf(ix), yf = floorf(iy);
    float tx = ix - xf, ty = iy - yf;
    int x0 = (int)xf, y0 = (int)yf;
    float w00 = (1.f - tx) * (1.f - ty) * aw, w01 = tx * (1.f - ty) * aw;
    float w10 = (1.f - tx) * ty * aw,         w11 = tx * ty * aw;
    int xs[4] = {x0, x0 + 1, x0, x0 + 1};
    int ys[4] = {y0, y0, y0 + 1, y0 + 1};
    float wg[4] = {w00, w01, w10, w11};
    #pragma unroll
    for (int cn = 0; cn < 4; ++cn) {
      int xx = xs[cn], yy = ys[cn];
      if ((unsigned)xx < 128u && (unsigned)yy < 128u) {
        u16x8 v = *(const u16x8*)(map + (((size_t)yy << 7) + xx) * DH);
        float wgt = wg[cn];
        #pragma unroll
        for (int jj = 0; jj < 8; ++jj) acc[jj] += wgt * bf2f(v[jj]);
      }
    }
  }
  u16x8 o;
  #pragma unroll
  for (int jj = 0; jj < 8; ++jj) o[jj] = f2bf(acc[jj]);
  *(u16x8*)(mid + ((size_t)h * Mrows + row) * DH + sub * 8) = o;
}

extern "C" void kernel_launch(void* const* d_in, const int* in_sizes, int n_in,
                              void* d_out, int out_size, void* d_ws, size_t ws_size,
                              hipStream_t stream) {
  const float* query = (const float*)d_in[0];
  const float* refp  = (const float*)d_in[1];
  const float* value = (const float*)d_in[2];
  const float* Wv    = (const float*)d_in[3];
  const float* bv    = (const float*)d_in[4];
  const float* Woff  = (const float*)d_in[5];
  const float* boff  = (const float*)d_in[6];
  const float* Wattn = (const float*)d_in[7];
  const float* battn = (const float*)d_in[8];
  const float* Wout  = (const float*)d_in[9];
  const float* bout  = (const float*)d_in[10];

  const int M = in_sizes[0] / CDIM;          // B*N = 65536

  char* ws = (char*)d_ws;
  unsigned short* vmap = (unsigned short*)ws;                 // M*256 bf16 = 33.5 MB
  size_t off1 = (size_t)M * CDIM * 2;
  float* loc = (float*)(ws + off1);                           // M*64 f32 = 16.8 MB
  size_t off2 = off1 + (size_t)M * 64 * 4;
  float* attnw = (float*)(ws + off2);                         // [h][M][4] f32 = 8.4 MB
  size_t off3 = off2 + (size_t)M * 32 * 4;
  unsigned short* mid = (unsigned short*)(ws + off3);         // [h][M][32] bf16 = 33.5 MB
  size_t off4 = off3 + (size_t)M * CDIM * 2;
  unsigned short* wvT = (unsigned short*)(ws + off4);         // 256x256 bf16 = 128 KB
  unsigned short* woT = wvT + CDIM * CDIM;                    // 256x256 bf16 = 128 KB

  hipLaunchKernelGGL(prep_k, dim3(4, 4, 2), dim3(256), 0, stream, Wv, Wout, wvT, woT);
  dim3 gg(M / 128, CDIM / 128);
  hipLaunchKernelGGL((gemm_k<false, 0>), gg, dim3(256), 0, stream, value, wvT, bv, vmap, M);
  hipLaunchKernelGGL(offattn_k, dim3(M / 64), dim3(256), 0, stream,
                     query, refp, Woff, boff, Wattn, battn, loc, attnw, M);
  hipLaunchKernelGGL(sample_k, dim3(8, M / 64), dim3(256), 0, stream,
                     vmap, loc, attnw, mid, M);
  hipLaunchKernelGGL((gemm_k<true, 1>), gg, dim3(256), 0, stream, mid, woT, bout,
                     (float*)d_out, M);
}

// Round 5
// 148.815 us; speedup vs baseline: 3.4204x; 1.0523x over previous
//
#include <hip/hip_runtime.h>

#define DH    32          // d_head
#define NH    8
#define NPTS  4
#define CDIM  256
#define HW    16384       // H*W = 128*128
#define HDIM  128

typedef __attribute__((ext_vector_type(8))) short bf16x8;
typedef __attribute__((ext_vector_type(4))) float f32x4;
typedef __attribute__((ext_vector_type(8))) unsigned short u16x8;

__device__ __forceinline__ unsigned short f2bf(float f) {
  unsigned u = __float_as_uint(f);
  u += 0x7FFFu + ((u >> 16) & 1u);          // round-to-nearest-even
  return (unsigned short)(u >> 16);
}
__device__ __forceinline__ float bf2f(unsigned short s) {
  return __uint_as_float(((unsigned)s) << 16);
}

// ---------------------------------------------------------------------------
// One-shot weight prep: f32 [k][col] (256x256) -> bf16 transposed [col][k].
// 64x64 LDS-tiled transpose; grid (4,4,2), z selects {Wv, Wout}.
// ---------------------------------------------------------------------------
__global__ __launch_bounds__(256) void prep_k(
    const float* __restrict__ W0, const float* __restrict__ W1,
    unsigned short* __restrict__ T0, unsigned short* __restrict__ T1) {
  __shared__ unsigned short tile[64][68];
  const float* W = blockIdx.z ? W1 : W0;
  unsigned short* T = blockIdx.z ? T1 : T0;
  const int r0 = blockIdx.x * 64, c0 = blockIdx.y * 64;
  const int t = threadIdx.x;
  #pragma unroll
  for (int i = 0; i < 4; ++i) {
    int f = t + i * 256;                     // 1024 float4
    int r = f >> 4, c4 = (f & 15) << 2;
    float4 v = *(const float4*)(W + (size_t)(r0 + r) * CDIM + c0 + c4);
    ushort4 s;
    s.x = f2bf(v.x); s.y = f2bf(v.y); s.z = f2bf(v.z); s.w = f2bf(v.w);
    *(ushort4*)&tile[r][c4] = s;
  }
  __syncthreads();
  #pragma unroll
  for (int i = 0; i < 4; ++i) {
    int f = t + i * 256;
    int c = f >> 4, r4 = (f & 15) << 2;
    ushort4 o;
    o.x = tile[r4 + 0][c]; o.y = tile[r4 + 1][c];
    o.z = tile[r4 + 2][c]; o.w = tile[r4 + 3][c];
    *(ushort4*)(T + (size_t)(c0 + c) * CDIM + r0 + r4) = o;
  }
}

// ---------------------------------------------------------------------------
// One-shot offset/attn weight prep: split hi/lo bf16, transposed [col][k].
// cols 0..63 = Woff, 64..95 = Wattn. grid(96), block = col, thread = k.
// ---------------------------------------------------------------------------
__global__ __launch_bounds__(256) void prepw_k(
    const float* __restrict__ Woff, const float* __restrict__ Wattn,
    unsigned short* __restrict__ Whi, unsigned short* __restrict__ Wlo) {
  const int c = blockIdx.x, k = threadIdx.x;
  float x = (c < 64) ? Woff[(size_t)k * 64 + c] : Wattn[(size_t)k * 32 + (c - 64)];
  unsigned short h = f2bf(x);
  Whi[(size_t)c * 256 + k] = h;
  Wlo[(size_t)c * 256 + k] = f2bf(x - bf2f(h));
}

// ---------------------------------------------------------------------------
// GEMM: C(M x 256) = A(M x 256) * B(256 x 256) + bias
// B: bf16 pre-transposed [col][k]. ABF16=false: A f32 row-major (value),
// converted during staging. ABF16=true: A bf16 head-major [h][M][32] (mid).
// EPI 0: scatter to vmap bf16 [b*8+h][n][c]; EPI 1: f32 row-major out.
// 128x128 tile, 4 waves (2x2), wave tile 64x64 (4x4 frags), BK=32.
// LDS rows padded to 36 shorts (odd word stride 18 -> conflict-free b128).
// ---------------------------------------------------------------------------
template<bool ABF16, int EPI>
__global__ __launch_bounds__(256) void gemm_k(
    const void* __restrict__ Ap, const unsigned short* __restrict__ Bt,
    const float* __restrict__ bias, void* __restrict__ Cp, int Mrows) {
  __shared__ unsigned short As[128][36];
  __shared__ unsigned short Bs[128][36];
  const int mt = blockIdx.x, ct = blockIdx.y;
  const int t = threadIdx.x;
  const int lane = t & 63, wv = t >> 6;
  const int wr = wv >> 1, wc = wv & 1;
  const int l15 = lane & 15, l4 = lane >> 4;

  f32x4 acc[4][4] = {};

  for (int kk = 0; kk < 8; ++kk) {
    if (!ABF16) {
      const float* A = (const float*)Ap;
      #pragma unroll
      for (int i = 0; i < 4; ++i) {
        int f = t + i * 256;                  // 1024 float4: 128 rows x 8
        int row = f >> 3, c4 = (f & 7) << 2;
        float4 v = *(const float4*)(A + (size_t)(mt * 128 + row) * CDIM + kk * 32 + c4);
        ushort4 s;
        s.x = f2bf(v.x); s.y = f2bf(v.y); s.z = f2bf(v.z); s.w = f2bf(v.w);
        *(ushort4*)&As[row][c4] = s;
      }
    } else {
      const unsigned short* A = (const unsigned short*)Ap;
      #pragma unroll
      for (int i = 0; i < 2; ++i) {
        int f = t + i * 256;                  // 512 u16x8: 128 rows x 4
        int row = f >> 2, c8 = (f & 3) << 3;
        *(u16x8*)&As[row][c8] =
            *(const u16x8*)(A + ((size_t)kk * Mrows + mt * 128 + row) * 32 + c8);
      }
    }
    #pragma unroll
    for (int i = 0; i < 2; ++i) {
      int f = t + i * 256;                    // 512 u16x8: 128 cols x 4
      int col = f >> 2, k8 = (f & 3) << 3;
      *(u16x8*)&Bs[col][k8] =
          *(const u16x8*)(Bt + (size_t)(ct * 128 + col) * CDIM + kk * 32 + k8);
    }
    __syncthreads();
    bf16x8 a[4], b[4];
    #pragma unroll
    for (int m = 0; m < 4; ++m) a[m] = *(const bf16x8*)&As[wr * 64 + m * 16 + l15][l4 * 8];
    #pragma unroll
    for (int n = 0; n < 4; ++n) b[n] = *(const bf16x8*)&Bs[wc * 64 + n * 16 + l15][l4 * 8];
    #pragma unroll
    for (int m = 0; m < 4; ++m)
      #pragma unroll
      for (int n = 0; n < 4; ++n)
        acc[m][n] = __builtin_amdgcn_mfma_f32_16x16x32_bf16(a[m], b[n], acc[m][n], 0, 0, 0);
    __syncthreads();
  }
  #pragma unroll
  for (int m = 0; m < 4; ++m) {
    #pragma unroll
    for (int n = 0; n < 4; ++n) {
      #pragma unroll
      for (int r = 0; r < 4; ++r) {
        int R = mt * 128 + wr * 64 + m * 16 + l4 * 4 + r;
        int Cg = ct * 128 + wc * 64 + n * 16 + l15;
        float v = acc[m][n][r] + bias[Cg];
        if (EPI == 0) {
          int b2 = R >> 14, ntok = R & (HW - 1);
          int h = Cg >> 5, c = Cg & 31;
          ((unsigned short*)Cp)[((size_t)(b2 * NH + h) * HW + ntok) * DH + c] = f2bf(v);
        } else {
          ((float*)Cp)[(size_t)R * CDIM + Cg] = v;
        }
      }
    }
  }
}

// ---------------------------------------------------------------------------
// Offsets + attention via split-precision bf16 MFMA (qh*wh + ql*wh + qh*wl).
// Weights pre-split/transposed by prepw_k -> staging is pure u16x8 copies.
// Block: 64 rows, 4 waves (2x2), wave tile 32r x 48c. LDS stride 36 (odd
// word stride -> conflict-free).
// Epilogue: cols<64 -> tanh offsets -> pixel coords; cols>=64 -> 4-wide
// softmax via shfl_xor(1,2) -> attnw [h][M][4].
// ---------------------------------------------------------------------------
__global__ __launch_bounds__(256) void offattn_k(
    const float* __restrict__ query, const float* __restrict__ refp,
    const unsigned short* __restrict__ Whi, const unsigned short* __restrict__ Wlo,
    const float* __restrict__ boff, const float* __restrict__ battn,
    float* __restrict__ loc, float* __restrict__ attnw, int Mrows) {
  __shared__ unsigned short Ah[64][36], Al[64][36];    // [row][k]
  __shared__ unsigned short Bh[96][36], Bl[96][36];    // [col][k]
  const int t = threadIdx.x;
  const int lane = t & 63, wv = t >> 6;
  const int wr = wv >> 1, wc = wv & 1;
  const int l15 = lane & 15, l4 = lane >> 4;
  const int row0 = blockIdx.x * 64;

  f32x4 acc[2][3] = {};

  for (int kk = 0; kk < 8; ++kk) {
    #pragma unroll
    for (int i = 0; i < 2; ++i) {
      int ff = t + i * 256;                 // 512 float4
      int row = ff >> 3, c4 = (ff & 7) << 2;
      float4 v = *(const float4*)(query + (size_t)(row0 + row) * CDIM + kk * 32 + c4);
      ushort4 hi, lo;
      hi.x = f2bf(v.x); lo.x = f2bf(v.x - bf2f(hi.x));
      hi.y = f2bf(v.y); lo.y = f2bf(v.y - bf2f(hi.y));
      hi.z = f2bf(v.z); lo.z = f2bf(v.z - bf2f(hi.z));
      hi.w = f2bf(v.w); lo.w = f2bf(v.w - bf2f(hi.w));
      *(ushort4*)&Ah[row][c4] = hi;
      *(ushort4*)&Al[row][c4] = lo;
    }
    {
      // stage W hi+lo: 96 cols x 32 k each = 768 u16x8 -> 3 per thread
      #pragma unroll
      for (int i = 0; i < 3; ++i) {
        int f = t + i * 256;
        int g = (f >= 384) ? f - 384 : f;
        int col = g >> 2, k8 = (g & 3) << 3;
        const unsigned short* src = ((f >= 384) ? Wlo : Whi)
            + (size_t)col * 256 + kk * 32 + k8;
        if (f >= 384) *(u16x8*)&Bl[col][k8] = *(const u16x8*)src;
        else          *(u16x8*)&Bh[col][k8] = *(const u16x8*)src;
      }
    }
    __syncthreads();
    bf16x8 ah0 = *(const bf16x8*)&Ah[wr * 32 + l15][l4 * 8];
    bf16x8 ah1 = *(const bf16x8*)&Ah[wr * 32 + 16 + l15][l4 * 8];
    bf16x8 al0 = *(const bf16x8*)&Al[wr * 32 + l15][l4 * 8];
    bf16x8 al1 = *(const bf16x8*)&Al[wr * 32 + 16 + l15][l4 * 8];
    #pragma unroll
    for (int c = 0; c < 3; ++c) {
      bf16x8 bh = *(const bf16x8*)&Bh[wc * 48 + c * 16 + l15][l4 * 8];
      bf16x8 bl = *(const bf16x8*)&Bl[wc * 48 + c * 16 + l15][l4 * 8];
      acc[0][c] = __builtin_amdgcn_mfma_f32_16x16x32_bf16(ah0, bh, acc[0][c], 0, 0, 0);
      acc[0][c] = __builtin_amdgcn_mfma_f32_16x16x32_bf16(al0, bh, acc[0][c], 0, 0, 0);
      acc[0][c] = __builtin_amdgcn_mfma_f32_16x16x32_bf16(ah0, bl, acc[0][c], 0, 0, 0);
      acc[1][c] = __builtin_amdgcn_mfma_f32_16x16x32_bf16(ah1, bh, acc[1][c], 0, 0, 0);
      acc[1][c] = __builtin_amdgcn_mfma_f32_16x16x32_bf16(al1, bh, acc[1][c], 0, 0, 0);
      acc[1][c] = __builtin_amdgcn_mfma_f32_16x16x32_bf16(ah1, bl, acc[1][c], 0, 0, 0);
    }
    __syncthreads();
  }

  #pragma unroll
  for (int c = 0; c < 3; ++c) {
    const int ctile = wc * 3 + c;           // 0..5
    const int col = ctile * 16 + l15;       // 0..95
    const float bias = (ctile < 4) ? boff[col] : battn[col - 64];
    #pragma unroll
    for (int m = 0; m < 2; ++m) {
      #pragma unroll
      for (int r = 0; r < 4; ++r) {
        const int row = row0 + wr * 32 + m * 16 + l4 * 4 + r;
        float v = acc[m][c][r] + bias;
        if (ctile < 4) {
          float off = tanhf(v) * 0.5f;
          float rp = refp[(size_t)row * 2 + (col & 1)];
          loc[(size_t)row * 64 + col] = (rp + off) * 128.0f - 0.5f;
        } else {
          int j = col - 64;
          float m1 = fmaxf(v, __shfl_xor(v, 1));
          float mm = fmaxf(m1, __shfl_xor(m1, 2));
          float e = expf(v - mm);
          float s = e;
          s += __shfl_xor(s, 1);
          s += __shfl_xor(s, 2);
          attnw[((size_t)(j >> 2) * Mrows + row) * 4 + (j & 3)] = e / s;
        }
      }
    }
  }
}

// ---------------------------------------------------------------------------
// Bilinear sampling + attn-weighted sum over points.
// RAW-RESHAPE QUIRK: output (b,n,h,p) uses loc of (n_l = h*2048 + (n>>3),
// h_l = n&7, p) on map (b,h). grid (8, M/64); blockIdx.x = h (head-per-XCD
// L2 locality). 4 consecutive lanes gather one 64B corner cooperatively.
// ---------------------------------------------------------------------------
__global__ __launch_bounds__(256) void sample_k(
    const unsigned short* __restrict__ vmap, const float* __restrict__ loc,
    const float* __restrict__ attnw, unsigned short* __restrict__ mid, int Mrows) {
  const int t = threadIdx.x;
  const int h = blockIdx.x;            // 0..7
  const int r = t >> 2;                // 0..63
  const int sub = t & 3;               // channel quad (8 channels, 16B)
  const int row = blockIdx.y * 64 + r;
  const int b = row >> 14, n = row & (HW - 1);
  const int n_l = h * 2048 + (n >> 3);
  const int h_l = n & 7;
  const float* lp = loc + (size_t)(b * HW + n_l) * 64 + h_l * 8;
  const f32x4 aq = *(const f32x4*)(attnw + ((size_t)h * Mrows + row) * 4);
  const unsigned short* map = vmap + (size_t)(b * NH + h) * HW * DH + sub * 8;

  f32x4 l01 = *(const f32x4*)(lp);      // p0.x p0.y p1.x p1.y
  f32x4 l23 = *(const f32x4*)(lp + 4);  // p2.x p2.y p3.x p3.y

  float acc[8];
  #pragma unroll
  for (int c = 0; c < 8; ++c) acc[c] = 0.f;

  #pragma unroll
  for (int p = 0; p < NPTS; ++p) {
    float ix = (p < 2) ? l01[(p & 1) * 2] : l23[(p & 1) * 2];
    float iy = (p < 2) ? l01[(p & 1) * 2 + 1] : l23[(p & 1) * 2 + 1];
    float aw = aq[p];
    float xf = floorf(ix), yf = floorf(iy);
    float tx = ix - xf, ty = iy - yf;
    int x0 = (int)xf, y0 = (int)yf;
    float w00 = (1.f - tx) * (1.f - ty) * aw, w01 = tx * (1.f - ty) * aw;
    float w10 = (1.f - tx) * ty * aw,         w11 = tx * ty * aw;
    int xs[4] = {x0, x0 + 1, x0, x0 + 1};
    int ys[4] = {y0, y0, y0 + 1, y0 + 1};
    float wg[4] = {w00, w01, w10, w11};
    #pragma unroll
    for (int cn = 0; cn < 4; ++cn) {
      int xx = xs[cn], yy = ys[cn];
      if ((unsigned)xx < 128u && (unsigned)yy < 128u) {
        u16x8 v = *(const u16x8*)(map + (((size_t)yy << 7) + xx) * DH);
        float wgt = wg[cn];
        #pragma unroll
        for (int jj = 0; jj < 8; ++jj) acc[jj] += wgt * bf2f(v[jj]);
      }
    }
  }
  u16x8 o;
  #pragma unroll
  for (int jj = 0; jj < 8; ++jj) o[jj] = f2bf(acc[jj]);
  *(u16x8*)(mid + ((size_t)h * Mrows + row) * DH + sub * 8) = o;
}

extern "C" void kernel_launch(void* const* d_in, const int* in_sizes, int n_in,
                              void* d_out, int out_size, void* d_ws, size_t ws_size,
                              hipStream_t stream) {
  const float* query = (const float*)d_in[0];
  const float* refp  = (const float*)d_in[1];
  const float* value = (const float*)d_in[2];
  const float* Wv    = (const float*)d_in[3];
  const float* bv    = (const float*)d_in[4];
  const float* Woff  = (const float*)d_in[5];
  const float* boff  = (const float*)d_in[6];
  const float* Wattn = (const float*)d_in[7];
  const float* battn = (const float*)d_in[8];
  const float* Wout  = (const float*)d_in[9];
  const float* bout  = (const float*)d_in[10];

  const int M = in_sizes[0] / CDIM;          // B*N = 65536

  char* ws = (char*)d_ws;
  unsigned short* vmap = (unsigned short*)ws;                 // M*256 bf16 = 33.5 MB
  size_t off1 = (size_t)M * CDIM * 2;
  float* loc = (float*)(ws + off1);                           // M*64 f32 = 16.8 MB
  size_t off2 = off1 + (size_t)M * 64 * 4;
  float* attnw = (float*)(ws + off2);                         // [h][M][4] f32 = 8.4 MB
  size_t off3 = off2 + (size_t)M * 32 * 4;
  unsigned short* mid = (unsigned short*)(ws + off3);         // [h][M][32] bf16 = 33.5 MB
  size_t off4 = off3 + (size_t)M * CDIM * 2;
  unsigned short* wvT = (unsigned short*)(ws + off4);         // 256x256 bf16 = 128 KB
  unsigned short* woT = wvT + CDIM * CDIM;                    // 256x256 bf16 = 128 KB
  unsigned short* Whi = woT + CDIM * CDIM;                    // 96x256 bf16 = 48 KB
  unsigned short* Wlo = Whi + 96 * CDIM;                      // 96x256 bf16 = 48 KB

  hipLaunchKernelGGL(prep_k, dim3(4, 4, 2), dim3(256), 0, stream, Wv, Wout, wvT, woT);
  hipLaunchKernelGGL(prepw_k, dim3(96), dim3(256), 0, stream, Woff, Wattn, Whi, Wlo);
  dim3 gg(M / 128, CDIM / 128);
  hipLaunchKernelGGL((gemm_k<false, 0>), gg, dim3(256), 0, stream, value, wvT, bv, vmap, M);
  hipLaunchKernelGGL(offattn_k, dim3(M / 64), dim3(256), 0, stream,
                     query, refp, Whi, Wlo, boff, battn, loc, attnw, M);
  hipLaunchKernelGGL(sample_k, dim3(8, M / 64), dim3(256), 0, stream,
                     vmap, loc, attnw, mid, M);
  hipLaunchKernelGGL((gemm_k<true, 1>), gg, dim3(256), 0, stream, mid, woT, bout,
                     (float*)d_out, M);
}

// Round 6
// 145.473 us; speedup vs baseline: 3.4990x; 1.0230x over previous
//
#include <hip/hip_runtime.h>

#define DH    32          // d_head
#define NH    8
#define NPTS  4
#define CDIM  256
#define HW    16384       // H*W = 128*128
#define HDIM  128

typedef __attribute__((ext_vector_type(8))) short bf16x8;
typedef __attribute__((ext_vector_type(4))) float f32x4;
typedef __attribute__((ext_vector_type(8))) unsigned short u16x8;

__device__ __forceinline__ unsigned short f2bf(float f) {
  unsigned u = __float_as_uint(f);
  u += 0x7FFFu + ((u >> 16) & 1u);          // round-to-nearest-even
  return (unsigned short)(u >> 16);
}
__device__ __forceinline__ float bf2f(unsigned short s) {
  return __uint_as_float(((unsigned)s) << 16);
}

// ---------------------------------------------------------------------------
// One-shot weight prep: f32 [k][col] (256x256) -> bf16 transposed [col][k].
// ---------------------------------------------------------------------------
__global__ __launch_bounds__(256) void prep_k(
    const float* __restrict__ W0, const float* __restrict__ W1,
    unsigned short* __restrict__ T0, unsigned short* __restrict__ T1) {
  __shared__ unsigned short tile[64][68];
  const float* W = blockIdx.z ? W1 : W0;
  unsigned short* T = blockIdx.z ? T1 : T0;
  const int r0 = blockIdx.x * 64, c0 = blockIdx.y * 64;
  const int t = threadIdx.x;
  #pragma unroll
  for (int i = 0; i < 4; ++i) {
    int f = t + i * 256;                     // 1024 float4
    int r = f >> 4, c4 = (f & 15) << 2;
    float4 v = *(const float4*)(W + (size_t)(r0 + r) * CDIM + c0 + c4);
    ushort4 s;
    s.x = f2bf(v.x); s.y = f2bf(v.y); s.z = f2bf(v.z); s.w = f2bf(v.w);
    *(ushort4*)&tile[r][c4] = s;
  }
  __syncthreads();
  #pragma unroll
  for (int i = 0; i < 4; ++i) {
    int f = t + i * 256;
    int c = f >> 4, r4 = (f & 15) << 2;
    ushort4 o;
    o.x = tile[r4 + 0][c]; o.y = tile[r4 + 1][c];
    o.z = tile[r4 + 2][c]; o.w = tile[r4 + 3][c];
    *(ushort4*)(T + (size_t)(c0 + c) * CDIM + r0 + r4) = o;
  }
}

// ---------------------------------------------------------------------------
// One-shot offset/attn weight prep: split hi/lo bf16, transposed [col][k].
// ---------------------------------------------------------------------------
__global__ __launch_bounds__(256) void prepw_k(
    const float* __restrict__ Woff, const float* __restrict__ Wattn,
    unsigned short* __restrict__ Whi, unsigned short* __restrict__ Wlo) {
  const int c = blockIdx.x, k = threadIdx.x;
  float x = (c < 64) ? Woff[(size_t)k * 64 + c] : Wattn[(size_t)k * 32 + (c - 64)];
  unsigned short h = f2bf(x);
  Whi[(size_t)c * 256 + k] = h;
  Wlo[(size_t)c * 256 + k] = f2bf(x - bf2f(h));
}

// ---------------------------------------------------------------------------
// GEMM: C(M x 256) = A(M x 256) * B(256 x 256) + bias
// 128x128 tile, 4 waves (2x2), wave tile 64x64, BK=32, LDS stride 36 (odd
// word stride -> conflict-free b128). 2-phase pipeline: double-buffered LDS,
// next tile's global loads issued into regs before the MFMA phase, ONE
// barrier per K-step (write buf b at iter k vs last reads at iter k-2 are
// separated by iter k-1's barrier).
// ---------------------------------------------------------------------------
template<bool ABF16, int EPI>
__global__ __launch_bounds__(256) void gemm_k(
    const void* __restrict__ Ap, const unsigned short* __restrict__ Bt,
    const float* __restrict__ bias, void* __restrict__ Cp, int Mrows) {
  __shared__ unsigned short As[2][128][36];
  __shared__ unsigned short Bs[2][128][36];
  const int mt = blockIdx.x, ct = blockIdx.y;
  const int t = threadIdx.x;
  const int lane = t & 63, wv = t >> 6;
  const int wr = wv >> 1, wc = wv & 1;
  const int l15 = lane & 15, l4 = lane >> 4;

  f32x4 acc[4][4] = {};
  float4 avf[4];                // staged A (f32 path)
  u16x8  avh[2];                // staged A (bf16 path)
  u16x8  bvh[2];                // staged B

  const float* Af = (const float*)Ap;
  const unsigned short* A16 = (const unsigned short*)Ap;

  auto load_tile = [&](int kk) {
    if (!ABF16) {
      #pragma unroll
      for (int i = 0; i < 4; ++i) {
        int f = t + i * 256;                  // 1024 float4: 128 rows x 8
        int row = f >> 3, c4 = (f & 7) << 2;
        avf[i] = *(const float4*)(Af + (size_t)(mt * 128 + row) * CDIM + kk * 32 + c4);
      }
    } else {
      #pragma unroll
      for (int i = 0; i < 2; ++i) {
        int f = t + i * 256;                  // 512 u16x8: 128 rows x 4
        int row = f >> 2, c8 = (f & 3) << 3;
        avh[i] = *(const u16x8*)(A16 + ((size_t)kk * Mrows + mt * 128 + row) * 32 + c8);
      }
    }
    #pragma unroll
    for (int i = 0; i < 2; ++i) {
      int f = t + i * 256;                    // 512 u16x8: 128 cols x 4
      int col = f >> 2, k8 = (f & 3) << 3;
      bvh[i] = *(const u16x8*)(Bt + (size_t)(ct * 128 + col) * CDIM + kk * 32 + k8);
    }
  };
  auto write_tile = [&](int b) {
    if (!ABF16) {
      #pragma unroll
      for (int i = 0; i < 4; ++i) {
        int f = t + i * 256;
        int row = f >> 3, c4 = (f & 7) << 2;
        ushort4 s;
        s.x = f2bf(avf[i].x); s.y = f2bf(avf[i].y);
        s.z = f2bf(avf[i].z); s.w = f2bf(avf[i].w);
        *(ushort4*)&As[b][row][c4] = s;
      }
    } else {
      #pragma unroll
      for (int i = 0; i < 2; ++i) {
        int f = t + i * 256;
        int row = f >> 2, c8 = (f & 3) << 3;
        *(u16x8*)&As[b][row][c8] = avh[i];
      }
    }
    #pragma unroll
    for (int i = 0; i < 2; ++i) {
      int f = t + i * 256;
      int col = f >> 2, k8 = (f & 3) << 3;
      *(u16x8*)&Bs[b][col][k8] = bvh[i];
    }
  };

  load_tile(0);
  #pragma unroll
  for (int kk = 0; kk < 8; ++kk) {
    const int b = kk & 1;
    write_tile(b);
    __syncthreads();
    if (kk < 7) load_tile(kk + 1);            // overlap with MFMA below
    bf16x8 a[4], bb[4];
    #pragma unroll
    for (int m = 0; m < 4; ++m) a[m] = *(const bf16x8*)&As[b][wr * 64 + m * 16 + l15][l4 * 8];
    #pragma unroll
    for (int n = 0; n < 4; ++n) bb[n] = *(const bf16x8*)&Bs[b][wc * 64 + n * 16 + l15][l4 * 8];
    #pragma unroll
    for (int m = 0; m < 4; ++m)
      #pragma unroll
      for (int n = 0; n < 4; ++n)
        acc[m][n] = __builtin_amdgcn_mfma_f32_16x16x32_bf16(a[m], bb[n], acc[m][n], 0, 0, 0);
  }
  #pragma unroll
  for (int m = 0; m < 4; ++m) {
    #pragma unroll
    for (int n = 0; n < 4; ++n) {
      #pragma unroll
      for (int r = 0; r < 4; ++r) {
        int R = mt * 128 + wr * 64 + m * 16 + l4 * 4 + r;
        int Cg = ct * 128 + wc * 64 + n * 16 + l15;
        float v = acc[m][n][r] + bias[Cg];
        if (EPI == 0) {
          int b2 = R >> 14, ntok = R & (HW - 1);
          int h = Cg >> 5, c = Cg & 31;
          ((unsigned short*)Cp)[((size_t)(b2 * NH + h) * HW + ntok) * DH + c] = f2bf(v);
        } else {
          ((float*)Cp)[(size_t)R * CDIM + Cg] = v;
        }
      }
    }
  }
}

// ---------------------------------------------------------------------------
// Offsets + attention via split-precision bf16 MFMA (qh*wh + ql*wh + qh*wl).
// Same 2-phase pipeline as gemm_k: double-buffered LDS, prefetch into regs,
// one barrier per K-step. Weights pre-split/transposed by prepw_k.
// ---------------------------------------------------------------------------
__global__ __launch_bounds__(256) void offattn_k(
    const float* __restrict__ query, const float* __restrict__ refp,
    const unsigned short* __restrict__ Whi, const unsigned short* __restrict__ Wlo,
    const float* __restrict__ boff, const float* __restrict__ battn,
    float* __restrict__ loc, float* __restrict__ attnw, int Mrows) {
  __shared__ unsigned short Ah[2][64][36], Al[2][64][36];    // [row][k]
  __shared__ unsigned short Bh[2][96][36], Bl[2][96][36];    // [col][k]
  const int t = threadIdx.x;
  const int lane = t & 63, wv = t >> 6;
  const int wr = wv >> 1, wc = wv & 1;
  const int l15 = lane & 15, l4 = lane >> 4;
  const int row0 = blockIdx.x * 64;

  f32x4 acc[2][3] = {};
  float4 qv[2];
  u16x8  wreg[3];

  auto load_tile = [&](int kk) {
    #pragma unroll
    for (int i = 0; i < 2; ++i) {
      int ff = t + i * 256;                 // 512 float4
      int row = ff >> 3, c4 = (ff & 7) << 2;
      qv[i] = *(const float4*)(query + (size_t)(row0 + row) * CDIM + kk * 32 + c4);
    }
    #pragma unroll
    for (int i = 0; i < 3; ++i) {
      int f = t + i * 256;
      int g = (f >= 384) ? f - 384 : f;
      int col = g >> 2, k8 = (g & 3) << 3;
      wreg[i] = *(const u16x8*)(((f >= 384) ? Wlo : Whi) + (size_t)col * 256 + kk * 32 + k8);
    }
  };
  auto write_tile = [&](int b) {
    #pragma unroll
    for (int i = 0; i < 2; ++i) {
      int ff = t + i * 256;
      int row = ff >> 3, c4 = (ff & 7) << 2;
      ushort4 hi, lo;
      hi.x = f2bf(qv[i].x); lo.x = f2bf(qv[i].x - bf2f(hi.x));
      hi.y = f2bf(qv[i].y); lo.y = f2bf(qv[i].y - bf2f(hi.y));
      hi.z = f2bf(qv[i].z); lo.z = f2bf(qv[i].z - bf2f(hi.z));
      hi.w = f2bf(qv[i].w); lo.w = f2bf(qv[i].w - bf2f(hi.w));
      *(ushort4*)&Ah[b][row][c4] = hi;
      *(ushort4*)&Al[b][row][c4] = lo;
    }
    #pragma unroll
    for (int i = 0; i < 3; ++i) {
      int f = t + i * 256;
      int g = (f >= 384) ? f - 384 : f;
      int col = g >> 2, k8 = (g & 3) << 3;
      if (f >= 384) *(u16x8*)&Bl[b][col][k8] = wreg[i];
      else          *(u16x8*)&Bh[b][col][k8] = wreg[i];
    }
  };

  load_tile(0);
  #pragma unroll
  for (int kk = 0; kk < 8; ++kk) {
    const int b = kk & 1;
    write_tile(b);
    __syncthreads();
    if (kk < 7) load_tile(kk + 1);
    bf16x8 ah0 = *(const bf16x8*)&Ah[b][wr * 32 + l15][l4 * 8];
    bf16x8 ah1 = *(const bf16x8*)&Ah[b][wr * 32 + 16 + l15][l4 * 8];
    bf16x8 al0 = *(const bf16x8*)&Al[b][wr * 32 + l15][l4 * 8];
    bf16x8 al1 = *(const bf16x8*)&Al[b][wr * 32 + 16 + l15][l4 * 8];
    #pragma unroll
    for (int c = 0; c < 3; ++c) {
      bf16x8 bh = *(const bf16x8*)&Bh[b][wc * 48 + c * 16 + l15][l4 * 8];
      bf16x8 bl = *(const bf16x8*)&Bl[b][wc * 48 + c * 16 + l15][l4 * 8];
      acc[0][c] = __builtin_amdgcn_mfma_f32_16x16x32_bf16(ah0, bh, acc[0][c], 0, 0, 0);
      acc[0][c] = __builtin_amdgcn_mfma_f32_16x16x32_bf16(al0, bh, acc[0][c], 0, 0, 0);
      acc[0][c] = __builtin_amdgcn_mfma_f32_16x16x32_bf16(ah0, bl, acc[0][c], 0, 0, 0);
      acc[1][c] = __builtin_amdgcn_mfma_f32_16x16x32_bf16(ah1, bh, acc[1][c], 0, 0, 0);
      acc[1][c] = __builtin_amdgcn_mfma_f32_16x16x32_bf16(al1, bh, acc[1][c], 0, 0, 0);
      acc[1][c] = __builtin_amdgcn_mfma_f32_16x16x32_bf16(ah1, bl, acc[1][c], 0, 0, 0);
    }
  }

  #pragma unroll
  for (int c = 0; c < 3; ++c) {
    const int ctile = wc * 3 + c;           // 0..5
    const int col = ctile * 16 + l15;       // 0..95
    const float bias = (ctile < 4) ? boff[col] : battn[col - 64];
    #pragma unroll
    for (int m = 0; m < 2; ++m) {
      #pragma unroll
      for (int r = 0; r < 4; ++r) {
        const int row = row0 + wr * 32 + m * 16 + l4 * 4 + r;
        float v = acc[m][c][r] + bias;
        if (ctile < 4) {
          float off = tanhf(v) * 0.5f;
          float rp = refp[(size_t)row * 2 + (col & 1)];
          loc[(size_t)row * 64 + col] = (rp + off) * 128.0f - 0.5f;
        } else {
          int j = col - 64;
          float m1 = fmaxf(v, __shfl_xor(v, 1));
          float mm = fmaxf(m1, __shfl_xor(m1, 2));
          float e = expf(v - mm);
          float s = e;
          s += __shfl_xor(s, 1);
          s += __shfl_xor(s, 2);
          attnw[((size_t)(j >> 2) * Mrows + row) * 4 + (j & 3)] = e / s;
        }
      }
    }
  }
}

// ---------------------------------------------------------------------------
// Bilinear sampling + attn-weighted sum over points.
// RAW-RESHAPE QUIRK: output (b,n,h,p) uses loc of (n_l = h*2048 + (n>>3),
// h_l = n&7, p) on map (b,h). grid (8, M/64); blockIdx.x = h (head-per-XCD
// L2 locality). 4 consecutive lanes gather one 64B corner cooperatively.
// ---------------------------------------------------------------------------
__global__ __launch_bounds__(256) void sample_k(
    const unsigned short* __restrict__ vmap, const float* __restrict__ loc,
    const float* __restrict__ attnw, unsigned short* __restrict__ mid, int Mrows) {
  const int t = threadIdx.x;
  const int h = blockIdx.x;            // 0..7
  const int r = t >> 2;                // 0..63
  const int sub = t & 3;               // channel quad (8 channels, 16B)
  const int row = blockIdx.y * 64 + r;
  const int b = row >> 14, n = row & (HW - 1);
  const int n_l = h * 2048 + (n >> 3);
  const int h_l = n & 7;
  const float* lp = loc + (size_t)(b * HW + n_l) * 64 + h_l * 8;
  const f32x4 aq = *(const f32x4*)(attnw + ((size_t)h * Mrows + row) * 4);
  const unsigned short* map = vmap + (size_t)(b * NH + h) * HW * DH + sub * 8;

  f32x4 l01 = *(const f32x4*)(lp);      // p0.x p0.y p1.x p1.y
  f32x4 l23 = *(const f32x4*)(lp + 4);  // p2.x p2.y p3.x p3.y

  float acc[8];
  #pragma unroll
  for (int c = 0; c < 8; ++c) acc[c] = 0.f;

  #pragma unroll
  for (int p = 0; p < NPTS; ++p) {
    float ix = (p < 2) ? l01[(p & 1) * 2] : l23[(p & 1) * 2];
    float iy = (p < 2) ? l01[(p & 1) * 2 + 1] : l23[(p & 1) * 2 + 1];
    float aw = aq[p];
    float xf = floorf(ix), yf = floorf(iy);
    float tx = ix - xf, ty = iy - yf;
    int x0 = (int)xf, y0 = (int)yf;
    float w00 = (1.f - tx) * (1.f - ty) * aw, w01 = tx * (1.f - ty) * aw;
    float w10 = (1.f - tx) * ty * aw,         w11 = tx * ty * aw;
    int xs[4] = {x0, x0 + 1, x0, x0 + 1};
    int ys[4] = {y0, y0, y0 + 1, y0 + 1};
    float wg[4] = {w00, w01, w10, w11};
    #pragma unroll
    for (int cn = 0; cn < 4; ++cn) {
      int xx = xs[cn], yy = ys[cn];
      if ((unsigned)xx < 128u && (unsigned)yy < 128u) {
        u16x8 v = *(const u16x8*)(map + (((size_t)yy << 7) + xx) * DH);
        float wgt = wg[cn];
        #pragma unroll
        for (int jj = 0; jj < 8; ++jj) acc[jj] += wgt * bf2f(v[jj]);
      }
    }
  }
  u16x8 o;
  #pragma unroll
  for (int jj = 0; jj < 8; ++jj) o[jj] = f2bf(acc[jj]);
  *(u16x8*)(mid + ((size_t)h * Mrows + row) * DH + sub * 8) = o;
}

extern "C" void kernel_launch(void* const* d_in, const int* in_sizes, int n_in,
                              void* d_out, int out_size, void* d_ws, size_t ws_size,
                              hipStream_t stream) {
  const float* query = (const float*)d_in[0];
  const float* refp  = (const float*)d_in[1];
  const float* value = (const float*)d_in[2];
  const float* Wv    = (const float*)d_in[3];
  const float* bv    = (const float*)d_in[4];
  const float* Woff  = (const float*)d_in[5];
  const float* boff  = (const float*)d_in[6];
  const float* Wattn = (const float*)d_in[7];
  const float* battn = (const float*)d_in[8];
  const float* Wout  = (const float*)d_in[9];
  const float* bout  = (const float*)d_in[10];

  const int M = in_sizes[0] / CDIM;          // B*N = 65536

  char* ws = (char*)d_ws;
  unsigned short* vmap = (unsigned short*)ws;                 // M*256 bf16 = 33.5 MB
  size_t off1 = (size_t)M * CDIM * 2;
  float* loc = (float*)(ws + off1);                           // M*64 f32 = 16.8 MB
  size_t off2 = off1 + (size_t)M * 64 * 4;
  float* attnw = (float*)(ws + off2);                         // [h][M][4] f32 = 8.4 MB
  size_t off3 = off2 + (size_t)M * 32 * 4;
  unsigned short* mid = (unsigned short*)(ws + off3);         // [h][M][32] bf16 = 33.5 MB
  size_t off4 = off3 + (size_t)M * CDIM * 2;
  unsigned short* wvT = (unsigned short*)(ws + off4);         // 256x256 bf16 = 128 KB
  unsigned short* woT = wvT + CDIM * CDIM;                    // 256x256 bf16 = 128 KB
  unsigned short* Whi = woT + CDIM * CDIM;                    // 96x256 bf16 = 48 KB
  unsigned short* Wlo = Whi + 96 * CDIM;                      // 96x256 bf16 = 48 KB

  hipLaunchKernelGGL(prep_k, dim3(4, 4, 2), dim3(256), 0, stream, Wv, Wout, wvT, woT);
  hipLaunchKernelGGL(prepw_k, dim3(96), dim3(256), 0, stream, Woff, Wattn, Whi, Wlo);
  dim3 gg(M / 128, CDIM / 128);
  hipLaunchKernelGGL((gemm_k<false, 0>), gg, dim3(256), 0, stream, value, wvT, bv, vmap, M);
  hipLaunchKernelGGL(offattn_k, dim3(M / 64), dim3(256), 0, stream,
                     query, refp, Whi, Wlo, boff, battn, loc, attnw, M);
  hipLaunchKernelGGL(sample_k, dim3(8, M / 64), dim3(256), 0, stream,
                     vmap, loc, attnw, mid, M);
  hipLaunchKernelGGL((gemm_k<true, 1>), gg, dim3(256), 0, stream, mid, woT, bout,
                     (float*)d_out, M);
}

// Round 7
// 137.864 us; speedup vs baseline: 3.6921x; 1.0552x over previous
//
#include <hip/hip_runtime.h>

#define DH    32          // d_head
#define NH    8
#define NPTS  4
#define CDIM  256
#define HW    16384       // H*W = 128*128
#define HDIM  128

typedef __attribute__((ext_vector_type(8))) short bf16x8;
typedef __attribute__((ext_vector_type(4))) float f32x4;
typedef __attribute__((ext_vector_type(8))) unsigned short u16x8;

__device__ __forceinline__ unsigned short f2bf(float f) {
  unsigned u = __float_as_uint(f);
  u += 0x7FFFu + ((u >> 16) & 1u);          // round-to-nearest-even
  return (unsigned short)(u >> 16);
}
__device__ __forceinline__ float bf2f(unsigned short s) {
  return __uint_as_float(((unsigned)s) << 16);
}

// ---------------------------------------------------------------------------
// One-shot weight prep: f32 [k][col] (256x256) -> bf16 transposed [col][k].
// ---------------------------------------------------------------------------
__global__ __launch_bounds__(256) void prep_k(
    const float* __restrict__ W0, const float* __restrict__ W1,
    unsigned short* __restrict__ T0, unsigned short* __restrict__ T1) {
  __shared__ unsigned short tile[64][68];
  const float* W = blockIdx.z ? W1 : W0;
  unsigned short* T = blockIdx.z ? T1 : T0;
  const int r0 = blockIdx.x * 64, c0 = blockIdx.y * 64;
  const int t = threadIdx.x;
  #pragma unroll
  for (int i = 0; i < 4; ++i) {
    int f = t + i * 256;                     // 1024 float4
    int r = f >> 4, c4 = (f & 15) << 2;
    float4 v = *(const float4*)(W + (size_t)(r0 + r) * CDIM + c0 + c4);
    ushort4 s;
    s.x = f2bf(v.x); s.y = f2bf(v.y); s.z = f2bf(v.z); s.w = f2bf(v.w);
    *(ushort4*)&tile[r][c4] = s;
  }
  __syncthreads();
  #pragma unroll
  for (int i = 0; i < 4; ++i) {
    int f = t + i * 256;
    int c = f >> 4, r4 = (f & 15) << 2;
    ushort4 o;
    o.x = tile[r4 + 0][c]; o.y = tile[r4 + 1][c];
    o.z = tile[r4 + 2][c]; o.w = tile[r4 + 3][c];
    *(ushort4*)(T + (size_t)(c0 + c) * CDIM + r0 + r4) = o;
  }
}

// ---------------------------------------------------------------------------
// One-shot offset/attn weight prep: split hi/lo bf16, transposed [col][k].
// ---------------------------------------------------------------------------
__global__ __launch_bounds__(256) void prepw_k(
    const float* __restrict__ Woff, const float* __restrict__ Wattn,
    unsigned short* __restrict__ Whi, unsigned short* __restrict__ Wlo) {
  const int c = blockIdx.x, k = threadIdx.x;
  float x = (c < 64) ? Woff[(size_t)k * 64 + c] : Wattn[(size_t)k * 32 + (c - 64)];
  unsigned short h = f2bf(x);
  Whi[(size_t)c * 256 + k] = h;
  Wlo[(size_t)c * 256 + k] = f2bf(x - bf2f(h));
}

// ---------------------------------------------------------------------------
// GEMM: C(M x 256) = A(M x 256) * B(256 x 256) + bias
// 128x128 tile, 4 waves (2x2), wave tile 64x64, BK=32, LDS stride 36.
// 2-phase pipeline: double-buffered LDS, reg prefetch, one barrier/K-step.
// ---------------------------------------------------------------------------
template<bool ABF16, int EPI>
__global__ __launch_bounds__(256) void gemm_k(
    const void* __restrict__ Ap, const unsigned short* __restrict__ Bt,
    const float* __restrict__ bias, void* __restrict__ Cp, int Mrows) {
  __shared__ unsigned short As[2][128][36];
  __shared__ unsigned short Bs[2][128][36];
  const int mt = blockIdx.x, ct = blockIdx.y;
  const int t = threadIdx.x;
  const int lane = t & 63, wv = t >> 6;
  const int wr = wv >> 1, wc = wv & 1;
  const int l15 = lane & 15, l4 = lane >> 4;

  f32x4 acc[4][4] = {};
  float4 avf[4];                // staged A (f32 path)
  u16x8  avh[2];                // staged A (bf16 path)
  u16x8  bvh[2];                // staged B

  const float* Af = (const float*)Ap;
  const unsigned short* A16 = (const unsigned short*)Ap;

  auto load_tile = [&](int kk) {
    if (!ABF16) {
      #pragma unroll
      for (int i = 0; i < 4; ++i) {
        int f = t + i * 256;                  // 1024 float4: 128 rows x 8
        int row = f >> 3, c4 = (f & 7) << 2;
        avf[i] = *(const float4*)(Af + (size_t)(mt * 128 + row) * CDIM + kk * 32 + c4);
      }
    } else {
      #pragma unroll
      for (int i = 0; i < 2; ++i) {
        int f = t + i * 256;                  // 512 u16x8: 128 rows x 4
        int row = f >> 2, c8 = (f & 3) << 3;
        avh[i] = *(const u16x8*)(A16 + ((size_t)kk * Mrows + mt * 128 + row) * 32 + c8);
      }
    }
    #pragma unroll
    for (int i = 0; i < 2; ++i) {
      int f = t + i * 256;                    // 512 u16x8: 128 cols x 4
      int col = f >> 2, k8 = (f & 3) << 3;
      bvh[i] = *(const u16x8*)(Bt + (size_t)(ct * 128 + col) * CDIM + kk * 32 + k8);
    }
  };
  auto write_tile = [&](int b) {
    if (!ABF16) {
      #pragma unroll
      for (int i = 0; i < 4; ++i) {
        int f = t + i * 256;
        int row = f >> 3, c4 = (f & 7) << 2;
        ushort4 s;
        s.x = f2bf(avf[i].x); s.y = f2bf(avf[i].y);
        s.z = f2bf(avf[i].z); s.w = f2bf(avf[i].w);
        *(ushort4*)&As[b][row][c4] = s;
      }
    } else {
      #pragma unroll
      for (int i = 0; i < 2; ++i) {
        int f = t + i * 256;
        int row = f >> 2, c8 = (f & 3) << 3;
        *(u16x8*)&As[b][row][c8] = avh[i];
      }
    }
    #pragma unroll
    for (int i = 0; i < 2; ++i) {
      int f = t + i * 256;
      int col = f >> 2, k8 = (f & 3) << 3;
      *(u16x8*)&Bs[b][col][k8] = bvh[i];
    }
  };

  load_tile(0);
  #pragma unroll
  for (int kk = 0; kk < 8; ++kk) {
    const int b = kk & 1;
    write_tile(b);
    __syncthreads();
    if (kk < 7) load_tile(kk + 1);            // overlap with MFMA below
    bf16x8 a[4], bb[4];
    #pragma unroll
    for (int m = 0; m < 4; ++m) a[m] = *(const bf16x8*)&As[b][wr * 64 + m * 16 + l15][l4 * 8];
    #pragma unroll
    for (int n = 0; n < 4; ++n) bb[n] = *(const bf16x8*)&Bs[b][wc * 64 + n * 16 + l15][l4 * 8];
    #pragma unroll
    for (int m = 0; m < 4; ++m)
      #pragma unroll
      for (int n = 0; n < 4; ++n)
        acc[m][n] = __builtin_amdgcn_mfma_f32_16x16x32_bf16(a[m], bb[n], acc[m][n], 0, 0, 0);
  }
  #pragma unroll
  for (int m = 0; m < 4; ++m) {
    #pragma unroll
    for (int n = 0; n < 4; ++n) {
      #pragma unroll
      for (int r = 0; r < 4; ++r) {
        int R = mt * 128 + wr * 64 + m * 16 + l4 * 4 + r;
        int Cg = ct * 128 + wc * 64 + n * 16 + l15;
        float v = acc[m][n][r] + bias[Cg];
        if (EPI == 0) {
          int b2 = R >> 14, ntok = R & (HW - 1);
          int h = Cg >> 5, c = Cg & 31;
          ((unsigned short*)Cp)[((size_t)(b2 * NH + h) * HW + ntok) * DH + c] = f2bf(v);
        } else {
          ((float*)Cp)[(size_t)R * CDIM + Cg] = v;
        }
      }
    }
  }
}

// ---------------------------------------------------------------------------
// Offsets + attention v3: barrier-free K-loop.
// Weights (hi/lo bf16, [col][k]) loaded into LDS ONCE per block (27KB x2,
// per-K-step subtiles, stride 36 = proven conflict-free). A (query f32) is
// read straight from global into MFMA fragments (lane l15 = row, l4*8 = k
// -> 2 x 16B contiguous per lane) and split hi/lo in-register. No LDS
// round-trip for A, no barriers after the initial weight load.
// Block: 512 thr (8 waves x 32 rows), grid (M/256, 2 col-halves of 48).
// ---------------------------------------------------------------------------
__global__ __launch_bounds__(512) void offattn_k(
    const float* __restrict__ query, const float* __restrict__ refp,
    const unsigned short* __restrict__ Whi, const unsigned short* __restrict__ Wlo,
    const float* __restrict__ boff, const float* __restrict__ battn,
    float* __restrict__ loc, float* __restrict__ attnw, int Mrows) {
  __shared__ unsigned short Bh[8][48][36], Bl[8][48][36];   // 54 KB
  const int t = threadIdx.x;
  const int lane = t & 63, w = t >> 6;
  const int l15 = lane & 15, l4 = lane >> 4;
  const int cy = blockIdx.y;                 // col-half: cols cy*48..cy*48+47
  const int row0 = blockIdx.x * 256 + w * 32;

  // one-time weight load: 48 cols x 256 k, hi+lo
  #pragma unroll
  for (int i = 0; i < 3; ++i) {
    int f = t + i * 512;                     // 0..1535
    int col = f >> 5;                        // 0..47
    int kg = (f & 31) << 3;                  // 0..248
    int kk = kg >> 5, ko = kg & 31;
    *(u16x8*)&Bh[kk][col][ko] = *(const u16x8*)(Whi + (size_t)(cy * 48 + col) * 256 + kg);
    *(u16x8*)&Bl[kk][col][ko] = *(const u16x8*)(Wlo + (size_t)(cy * 48 + col) * 256 + kg);
  }
  __syncthreads();

  f32x4 acc[2][3] = {};

  #pragma unroll
  for (int kk = 0; kk < 8; ++kk) {
    bf16x8 ah[2], al[2];
    #pragma unroll
    for (int m = 0; m < 2; ++m) {
      const float* p = query + (size_t)(row0 + m * 16 + l15) * CDIM + kk * 32 + l4 * 8;
      f32x4 v0 = *(const f32x4*)p;
      f32x4 v1 = *(const f32x4*)(p + 4);
      #pragma unroll
      for (int i = 0; i < 4; ++i) {
        unsigned short h0 = f2bf(v0[i]);
        ah[m][i] = (short)h0;
        al[m][i] = (short)f2bf(v0[i] - bf2f(h0));
        unsigned short h1 = f2bf(v1[i]);
        ah[m][4 + i] = (short)h1;
        al[m][4 + i] = (short)f2bf(v1[i] - bf2f(h1));
      }
    }
    #pragma unroll
    for (int c = 0; c < 3; ++c) {
      bf16x8 bh = *(const bf16x8*)&Bh[kk][c * 16 + l15][l4 * 8];
      bf16x8 bl = *(const bf16x8*)&Bl[kk][c * 16 + l15][l4 * 8];
      acc[0][c] = __builtin_amdgcn_mfma_f32_16x16x32_bf16(ah[0], bh, acc[0][c], 0, 0, 0);
      acc[0][c] = __builtin_amdgcn_mfma_f32_16x16x32_bf16(al[0], bh, acc[0][c], 0, 0, 0);
      acc[0][c] = __builtin_amdgcn_mfma_f32_16x16x32_bf16(ah[0], bl, acc[0][c], 0, 0, 0);
      acc[1][c] = __builtin_amdgcn_mfma_f32_16x16x32_bf16(ah[1], bh, acc[1][c], 0, 0, 0);
      acc[1][c] = __builtin_amdgcn_mfma_f32_16x16x32_bf16(al[1], bh, acc[1][c], 0, 0, 0);
      acc[1][c] = __builtin_amdgcn_mfma_f32_16x16x32_bf16(ah[1], bl, acc[1][c], 0, 0, 0);
    }
  }

  #pragma unroll
  for (int c = 0; c < 3; ++c) {
    const int gct = cy * 3 + c;             // global col-tile 0..5
    const int col = gct * 16 + l15;         // 0..95
    const float bias = (gct < 4) ? boff[col] : battn[col - 64];
    #pragma unroll
    for (int m = 0; m < 2; ++m) {
      #pragma unroll
      for (int r = 0; r < 4; ++r) {
        const int row = row0 + m * 16 + l4 * 4 + r;
        float v = acc[m][c][r] + bias;
        if (gct < 4) {
          float off = tanhf(v) * 0.5f;
          float rp = refp[(size_t)row * 2 + (col & 1)];
          loc[(size_t)row * 64 + col] = (rp + off) * 128.0f - 0.5f;
        } else {
          int j = col - 64;
          float m1 = fmaxf(v, __shfl_xor(v, 1));
          float mm = fmaxf(m1, __shfl_xor(m1, 2));
          float e = expf(v - mm);
          float s = e;
          s += __shfl_xor(s, 1);
          s += __shfl_xor(s, 2);
          attnw[((size_t)(j >> 2) * Mrows + row) * 4 + (j & 3)] = e / s;
        }
      }
    }
  }
}

// ---------------------------------------------------------------------------
// Bilinear sampling + attn-weighted sum over points.
// RAW-RESHAPE QUIRK: output (b,n,h,p) uses loc of (n_l = h*2048 + (n>>3),
// h_l = n&7, p) on map (b,h). grid (8, M/64); blockIdx.x = h (head-per-XCD
// L2 locality). 4 consecutive lanes gather one 64B corner cooperatively.
// ---------------------------------------------------------------------------
__global__ __launch_bounds__(256) void sample_k(
    const unsigned short* __restrict__ vmap, const float* __restrict__ loc,
    const float* __restrict__ attnw, unsigned short* __restrict__ mid, int Mrows) {
  const int t = threadIdx.x;
  const int h = blockIdx.x;            // 0..7
  const int r = t >> 2;                // 0..63
  const int sub = t & 3;               // channel quad (8 channels, 16B)
  const int row = blockIdx.y * 64 + r;
  const int b = row >> 14, n = row & (HW - 1);
  const int n_l = h * 2048 + (n >> 3);
  const int h_l = n & 7;
  const float* lp = loc + (size_t)(b * HW + n_l) * 64 + h_l * 8;
  const f32x4 aq = *(const f32x4*)(attnw + ((size_t)h * Mrows + row) * 4);
  const unsigned short* map = vmap + (size_t)(b * NH + h) * HW * DH + sub * 8;

  f32x4 l01 = *(const f32x4*)(lp);      // p0.x p0.y p1.x p1.y
  f32x4 l23 = *(const f32x4*)(lp + 4);  // p2.x p2.y p3.x p3.y

  float acc[8];
  #pragma unroll
  for (int c = 0; c < 8; ++c) acc[c] = 0.f;

  #pragma unroll
  for (int p = 0; p < NPTS; ++p) {
    float ix = (p < 2) ? l01[(p & 1) * 2] : l23[(p & 1) * 2];
    float iy = (p < 2) ? l01[(p & 1) * 2 + 1] : l23[(p & 1) * 2 + 1];
    float aw = aq[p];
    float xf = floorf(ix), yf = floorf(iy);
    float tx = ix - xf, ty = iy - yf;
    int x0 = (int)xf, y0 = (int)yf;
    float w00 = (1.f - tx) * (1.f - ty) * aw, w01 = tx * (1.f - ty) * aw;
    float w10 = (1.f - tx) * ty * aw,         w11 = tx * ty * aw;
    int xs[4] = {x0, x0 + 1, x0, x0 + 1};
    int ys[4] = {y0, y0, y0 + 1, y0 + 1};
    float wg[4] = {w00, w01, w10, w11};
    #pragma unroll
    for (int cn = 0; cn < 4; ++cn) {
      int xx = xs[cn], yy = ys[cn];
      if ((unsigned)xx < 128u && (unsigned)yy < 128u) {
        u16x8 v = *(const u16x8*)(map + (((size_t)yy << 7) + xx) * DH);
        float wgt = wg[cn];
        #pragma unroll
        for (int jj = 0; jj < 8; ++jj) acc[jj] += wgt * bf2f(v[jj]);
      }
    }
  }
  u16x8 o;
  #pragma unroll
  for (int jj = 0; jj < 8; ++jj) o[jj] = f2bf(acc[jj]);
  *(u16x8*)(mid + ((size_t)h * Mrows + row) * DH + sub * 8) = o;
}

extern "C" void kernel_launch(void* const* d_in, const int* in_sizes, int n_in,
                              void* d_out, int out_size, void* d_ws, size_t ws_size,
                              hipStream_t stream) {
  const float* query = (const float*)d_in[0];
  const float* refp  = (const float*)d_in[1];
  const float* value = (const float*)d_in[2];
  const float* Wv    = (const float*)d_in[3];
  const float* bv    = (const float*)d_in[4];
  const float* Woff  = (const float*)d_in[5];
  const float* boff  = (const float*)d_in[6];
  const float* Wattn = (const float*)d_in[7];
  const float* battn = (const float*)d_in[8];
  const float* Wout  = (const float*)d_in[9];
  const float* bout  = (const float*)d_in[10];

  const int M = in_sizes[0] / CDIM;          // B*N = 65536

  char* ws = (char*)d_ws;
  unsigned short* vmap = (unsigned short*)ws;                 // M*256 bf16 = 33.5 MB
  size_t off1 = (size_t)M * CDIM * 2;
  float* loc = (float*)(ws + off1);                           // M*64 f32 = 16.8 MB
  size_t off2 = off1 + (size_t)M * 64 * 4;
  float* attnw = (float*)(ws + off2);                         // [h][M][4] f32 = 8.4 MB
  size_t off3 = off2 + (size_t)M * 32 * 4;
  unsigned short* mid = (unsigned short*)(ws + off3);         // [h][M][32] bf16 = 33.5 MB
  size_t off4 = off3 + (size_t)M * CDIM * 2;
  unsigned short* wvT = (unsigned short*)(ws + off4);         // 256x256 bf16 = 128 KB
  unsigned short* woT = wvT + CDIM * CDIM;                    // 256x256 bf16 = 128 KB
  unsigned short* Whi = woT + CDIM * CDIM;                    // 96x256 bf16 = 48 KB
  unsigned short* Wlo = Whi + 96 * CDIM;                      // 96x256 bf16 = 48 KB

  hipLaunchKernelGGL(prep_k, dim3(4, 4, 2), dim3(256), 0, stream, Wv, Wout, wvT, woT);
  hipLaunchKernelGGL(prepw_k, dim3(96), dim3(256), 0, stream, Woff, Wattn, Whi, Wlo);
  dim3 gg(M / 128, CDIM / 128);
  hipLaunchKernelGGL((gemm_k<false, 0>), gg, dim3(256), 0, stream, value, wvT, bv, vmap, M);
  hipLaunchKernelGGL(offattn_k, dim3(M / 256, 2), dim3(512), 0, stream,
                     query, refp, Whi, Wlo, boff, battn, loc, attnw, M);
  hipLaunchKernelGGL(sample_k, dim3(8, M / 64), dim3(256), 0, stream,
                     vmap, loc, attnw, mid, M);
  hipLaunchKernelGGL((gemm_k<true, 1>), gg, dim3(256), 0, stream, mid, woT, bout,
                     (float*)d_out, M);
}